// Round 1
// baseline (6727.782 us; speedup 1.0000x reference)
//
#include <hip/hip_runtime.h>

#define N_NODES 50000
#define N_EDGES 800000
#define TOT_E   (N_EDGES + N_NODES)   // with self loops
#define HEADS   8
#define HID     32
#define HC      256                   // HEADS*HID
#define NG      64

// ---- workspace layout (float offsets) ----
#define H_OFF     0               // h: N*256            (aliased as agg later)
#define AS_OFF    12800000        // a_s: N*8
#define AD_OFF    13200000        // a_d: N*8
#define OUT_OFF   13600000        // out: N*256          [zero-init]
#define M_OFF     26400000        // m (mapped uint): N*8 [zero-init]
#define DEN_OFF   26800000        // denom: N*8           [zero-init]
#define POOL_OFF  27200000        // pooled sums: 64*32   [zero-init]
#define CNT_OFF   27202048        // counts: 64           [zero-init]
#define WS_END    27202112
#define AGG_OFF   H_OFF

// monotone float<->uint mapping for atomicMax on signed floats
__device__ __forceinline__ unsigned fmap(float f) {
    unsigned u = __float_as_uint(f);
    return (u & 0x80000000u) ? ~u : (u | 0x80000000u);
}
__device__ __forceinline__ float funmap(unsigned u) {
    return (u & 0x80000000u) ? __uint_as_float(u & 0x7FFFFFFFu)
                             : __uint_as_float(~u);
}

__global__ __launch_bounds__(256) void k_zero(float* __restrict__ p, int n4) {
    int i = blockIdx.x * 256 + threadIdx.x;
    if (i < n4) ((float4*)p)[i] = make_float4(0.f, 0.f, 0.f, 0.f);
}

// h = x @ W_gat   (50000x128 @ 128x256), 16 nodes per block
__global__ __launch_bounds__(256) void k_gemm_h(const float* __restrict__ x,
                                                const float* __restrict__ Wg,
                                                float* __restrict__ h) {
    __shared__ float xs[16 * 128];
    int t = threadIdx.x;
    int n0 = blockIdx.x * 16;
#pragma unroll
    for (int r = 0; r < 8; ++r) {
        int idx = t + r * 256;
        xs[idx] = x[n0 * 128 + idx];
    }
    __syncthreads();
    float acc[16];
#pragma unroll
    for (int i = 0; i < 16; ++i) acc[i] = 0.f;
    for (int k = 0; k < 128; k += 4) {
        float w0 = Wg[(k + 0) * 256 + t];
        float w1 = Wg[(k + 1) * 256 + t];
        float w2 = Wg[(k + 2) * 256 + t];
        float w3 = Wg[(k + 3) * 256 + t];
#pragma unroll
        for (int i = 0; i < 16; ++i) {
            float4 xv = *(const float4*)&xs[i * 128 + k];
            acc[i] = fmaf(xv.x, w0, acc[i]);
            acc[i] = fmaf(xv.y, w1, acc[i]);
            acc[i] = fmaf(xv.z, w2, acc[i]);
            acc[i] = fmaf(xv.w, w3, acc[i]);
        }
    }
#pragma unroll
    for (int i = 0; i < 16; ++i) h[(n0 + i) * 256 + t] = acc[i];
}

// a_s[n,h] = sum_c h[n,h,c]*att_src[h,c];  a_d likewise. one thread per (n,head)
__global__ __launch_bounds__(256) void k_attn_coef(const float* __restrict__ h,
                                                   const float* __restrict__ att_s,
                                                   const float* __restrict__ att_d,
                                                   float* __restrict__ a_s,
                                                   float* __restrict__ a_d) {
    int t = blockIdx.x * 256 + threadIdx.x;
    if (t >= N_NODES * HEADS) return;
    int n = t >> 3, hd = t & 7;
    const float* hp = h + n * HC + hd * HID;
    const float* sp = att_s + hd * HID;
    const float* dp = att_d + hd * HID;
    float as = 0.f, ad = 0.f;
#pragma unroll
    for (int c = 0; c < HID; c += 4) {
        float4 hv = *(const float4*)(hp + c);
        float4 sv = *(const float4*)(sp + c);
        float4 dv = *(const float4*)(dp + c);
        as += hv.x * sv.x + hv.y * sv.y + hv.z * sv.z + hv.w * sv.w;
        ad += hv.x * dv.x + hv.y * dv.y + hv.z * dv.z + hv.w * dv.w;
    }
    a_s[t] = as;
    a_d[t] = ad;
}

__device__ __forceinline__ void edge_sd(const int* __restrict__ ei, int e, int& s, int& d) {
    if (e < N_EDGES) { s = ei[e]; d = ei[N_EDGES + e]; }
    else             { s = e - N_EDGES; d = s; }
}

// pass 1: per-dst max of leaky_relu(a_s[src]+a_d[dst])
__global__ __launch_bounds__(256) void k_edge_max(const int* __restrict__ ei,
                                                  const float* __restrict__ a_s,
                                                  const float* __restrict__ a_d,
                                                  unsigned* __restrict__ m) {
    int e = blockIdx.x * 256 + threadIdx.x;
    if (e >= TOT_E) return;
    int s, d; edge_sd(ei, e, s, d);
    float4 s0 = *(const float4*)(a_s + s * 8);
    float4 s1 = *(const float4*)(a_s + s * 8 + 4);
    float4 d0 = *(const float4*)(a_d + d * 8);
    float4 d1 = *(const float4*)(a_d + d * 8 + 4);
    float ev[8] = {s0.x + d0.x, s0.y + d0.y, s0.z + d0.z, s0.w + d0.w,
                   s1.x + d1.x, s1.y + d1.y, s1.z + d1.z, s1.w + d1.w};
#pragma unroll
    for (int hd = 0; hd < 8; ++hd) {
        float v = ev[hd];
        v = v > 0.f ? v : 0.2f * v;
        atomicMax(&m[d * 8 + hd], fmap(v));
    }
}

// pass 2: denom[dst] += exp(e - m[dst])
__global__ __launch_bounds__(256) void k_edge_den(const int* __restrict__ ei,
                                                  const float* __restrict__ a_s,
                                                  const float* __restrict__ a_d,
                                                  const unsigned* __restrict__ m,
                                                  float* __restrict__ den) {
    int e = blockIdx.x * 256 + threadIdx.x;
    if (e >= TOT_E) return;
    int s, d; edge_sd(ei, e, s, d);
    float4 s0 = *(const float4*)(a_s + s * 8);
    float4 s1 = *(const float4*)(a_s + s * 8 + 4);
    float4 d0 = *(const float4*)(a_d + d * 8);
    float4 d1 = *(const float4*)(a_d + d * 8 + 4);
    float ev[8] = {s0.x + d0.x, s0.y + d0.y, s0.z + d0.z, s0.w + d0.w,
                   s1.x + d1.x, s1.y + d1.y, s1.z + d1.z, s1.w + d1.w};
#pragma unroll
    for (int hd = 0; hd < 8; ++hd) {
        float v = ev[hd];
        v = v > 0.f ? v : 0.2f * v;
        float mm = funmap(m[d * 8 + hd]);
        atomicAdd(&den[d * 8 + hd], __expf(v - mm));
    }
}

// pass 3: out[dst] += alpha * h[src]; 64 threads per edge (4 ch each)
__global__ __launch_bounds__(256) void k_edge_agg(const int* __restrict__ ei,
                                                  const float* __restrict__ a_s,
                                                  const float* __restrict__ a_d,
                                                  const unsigned* __restrict__ m,
                                                  const float* __restrict__ den,
                                                  const float* __restrict__ h,
                                                  float* __restrict__ out) {
    int t = blockIdx.x * 256 + threadIdx.x;
    int e = t >> 6;
    if (e >= TOT_E) return;
    int lane = t & 63;
    int s, d; edge_sd(ei, e, s, d);
    int hd = lane >> 3;
    float v = a_s[s * 8 + hd] + a_d[d * 8 + hd];
    v = v > 0.f ? v : 0.2f * v;
    float alpha = __expf(v - funmap(m[d * 8 + hd])) / den[d * 8 + hd];
    float4 hv = *(const float4*)(h + s * HC + lane * 4);
    float* op = out + d * HC + lane * 4;
    atomicAdd(op + 0, alpha * hv.x);
    atomicAdd(op + 1, alpha * hv.y);
    atomicAdd(op + 2, alpha * hv.z);
    atomicAdd(op + 3, alpha * hv.w);
}

// out = relu(out + b_gat); agg = out  (agg aliases old h buffer)
__global__ __launch_bounds__(256) void k_bias_relu(float* __restrict__ out,
                                                   float* __restrict__ agg,
                                                   const float* __restrict__ bg) {
    int i = blockIdx.x * 256 + threadIdx.x; // float4 index
    if (i >= N_NODES * (HC / 4)) return;
    int c4 = i & 63;
    float4 v = ((float4*)out)[i];
    float4 b = ((const float4*)bg)[c4];
    v.x = fmaxf(v.x + b.x, 0.f);
    v.y = fmaxf(v.y + b.y, 0.f);
    v.z = fmaxf(v.z + b.z, 0.f);
    v.w = fmaxf(v.w + b.w, 0.f);
    ((float4*)out)[i] = v;
    ((float4*)agg)[i] = v;
}

// GIN aggregation over ORIGINAL edges only: agg[dst] += out[src]
__global__ __launch_bounds__(256) void k_gin(const int* __restrict__ ei,
                                             const float* __restrict__ out,
                                             float* __restrict__ agg) {
    int t = blockIdx.x * 256 + threadIdx.x;
    int e = t >> 6;
    if (e >= N_EDGES) return;
    int lane = t & 63;
    int s = ei[e], d = ei[N_EDGES + e];
    float4 v = *(const float4*)(out + s * HC + lane * 4);
    float* ap = agg + d * HC + lane * 4;
    atomicAdd(ap + 0, v.x);
    atomicAdd(ap + 1, v.y);
    atomicAdd(ap + 2, v.z);
    atomicAdd(ap + 3, v.w);
}

__global__ __launch_bounds__(256) void k_count(const int* __restrict__ batch,
                                               float* __restrict__ cnt) {
    int n = blockIdx.x * 256 + threadIdx.x;
    if (n >= N_NODES) return;
    atomicAdd(&cnt[batch[n]], 1.0f);
}

// z = relu(relu(agg@W1+b1)@W2+b2); pooled[batch[n]] += z. 8 nodes/block.
__global__ __launch_bounds__(256) void k_mlp_pool(const float* __restrict__ agg,
                                                  const int* __restrict__ batch,
                                                  const float* __restrict__ W1,
                                                  const float* __restrict__ b1,
                                                  const float* __restrict__ W2,
                                                  const float* __restrict__ b2,
                                                  float* __restrict__ pooled) {
    __shared__ float W1s[256 * 32];
    __shared__ float W2s[32 * 32];
    __shared__ float aggt[8 * 256];
    __shared__ float z1s[8 * 32];
    int t = threadIdx.x;
    int n0 = blockIdx.x * 8;
#pragma unroll
    for (int r = 0; r < 8; ++r)
        ((float4*)W1s)[t + r * 256] = ((const float4*)W1)[t + r * 256];
    ((float4*)W2s)[t] = ((const float4*)W2)[t];
#pragma unroll
    for (int r = 0; r < 2; ++r)
        ((float4*)aggt)[t + r * 256] = ((const float4*)(agg + n0 * HC))[t + r * 256];
    __syncthreads();
    int node = t >> 5, col = t & 31;
    float acc = b1[col];
    const float* ar = aggt + node * 256;
    for (int k = 0; k < 256; k += 4) {
        float4 av = *(const float4*)(ar + k);
        acc = fmaf(av.x, W1s[(k + 0) * 32 + col], acc);
        acc = fmaf(av.y, W1s[(k + 1) * 32 + col], acc);
        acc = fmaf(av.z, W1s[(k + 2) * 32 + col], acc);
        acc = fmaf(av.w, W1s[(k + 3) * 32 + col], acc);
    }
    z1s[node * 32 + col] = fmaxf(acc, 0.f);
    __syncthreads();
    float acc2 = b2[col];
    const float* zr = z1s + node * 32;
#pragma unroll
    for (int k = 0; k < 32; k += 4) {
        float4 zv = *(const float4*)(zr + k);
        acc2 = fmaf(zv.x, W2s[(k + 0) * 32 + col], acc2);
        acc2 = fmaf(zv.y, W2s[(k + 1) * 32 + col], acc2);
        acc2 = fmaf(zv.z, W2s[(k + 2) * 32 + col], acc2);
        acc2 = fmaf(zv.w, W2s[(k + 3) * 32 + col], acc2);
    }
    acc2 = fmaxf(acc2, 0.f);
    int g = batch[n0 + node];
    atomicAdd(&pooled[g * 32 + col], acc2);
}

// final: out[g,c] = (sum_k pooled[g,k]*Wf[k,c]) / max(cnt,1) + bf[c]
__global__ __launch_bounds__(128) void k_final(const float* __restrict__ pooled,
                                               const float* __restrict__ cnt,
                                               const float* __restrict__ Wf,
                                               const float* __restrict__ bf,
                                               float* __restrict__ outp) {
    int g = blockIdx.x, c = threadIdx.x;
    float inv = 1.0f / fmaxf(cnt[g], 1.0f);
    float acc = 0.f;
#pragma unroll
    for (int k = 0; k < 32; ++k)
        acc = fmaf(pooled[g * 32 + k], Wf[k * 128 + c], acc);
    outp[g * 128 + c] = acc * inv + bf[c];
}

extern "C" void kernel_launch(void* const* d_in, const int* in_sizes, int n_in,
                              void* d_out, int out_size, void* d_ws, size_t ws_size,
                              hipStream_t stream) {
    const float* x     = (const float*)d_in[0];
    const int*   ei    = (const int*)d_in[1];
    const int*   batch = (const int*)d_in[2];
    const float* Wg    = (const float*)d_in[3];
    const float* att_s = (const float*)d_in[4];
    const float* att_d = (const float*)d_in[5];
    const float* bg    = (const float*)d_in[6];
    const float* W1    = (const float*)d_in[7];
    const float* b1    = (const float*)d_in[8];
    const float* W2    = (const float*)d_in[9];
    const float* b2    = (const float*)d_in[10];
    const float* Wf    = (const float*)d_in[11];
    const float* bf    = (const float*)d_in[12];
    float* ws = (float*)d_ws;

    float*    h      = ws + H_OFF;
    float*    a_s    = ws + AS_OFF;
    float*    a_d    = ws + AD_OFF;
    float*    out    = ws + OUT_OFF;
    unsigned* m      = (unsigned*)(ws + M_OFF);
    float*    den    = ws + DEN_OFF;
    float*    pooled = ws + POOL_OFF;
    float*    cnt    = ws + CNT_OFF;
    float*    agg    = ws + AGG_OFF;

    // zero [OUT_OFF, WS_END): out, m, den, pooled, cnt
    int zero_n4 = (WS_END - OUT_OFF) / 4;
    k_zero<<<(zero_n4 + 255) / 256, 256, 0, stream>>>(ws + OUT_OFF, zero_n4);

    k_gemm_h<<<N_NODES / 16, 256, 0, stream>>>(x, Wg, h);
    k_attn_coef<<<(N_NODES * HEADS + 255) / 256, 256, 0, stream>>>(h, att_s, att_d, a_s, a_d);
    k_edge_max<<<(TOT_E + 255) / 256, 256, 0, stream>>>(ei, a_s, a_d, m);
    k_edge_den<<<(TOT_E + 255) / 256, 256, 0, stream>>>(ei, a_s, a_d, m, den);
    k_edge_agg<<<(TOT_E * 64 + 255) / 256, 256, 0, stream>>>(ei, a_s, a_d, m, den, h, out);
    k_bias_relu<<<(N_NODES * (HC / 4) + 255) / 256, 256, 0, stream>>>(out, agg, bg);
    k_gin<<<(N_EDGES * 64 + 255) / 256, 256, 0, stream>>>(ei, out, agg);
    k_count<<<(N_NODES + 255) / 256, 256, 0, stream>>>(batch, cnt);
    k_mlp_pool<<<N_NODES / 8, 256, 0, stream>>>(agg, batch, W1, b1, W2, b2, pooled);
    k_final<<<NG, 128, 0, stream>>>(pooled, cnt, Wf, bf, (float*)d_out);
}

// Round 2
// 981.722 us; speedup vs baseline: 6.8530x; 6.8530x over previous
//
#include <hip/hip_runtime.h>

#define N_NODES 50000
#define N_EDGES 800000
#define HEADS   8
#define HID     32
#define HC      256
#define NG      64
#define MAXD    128   // per-node LDS edge cache; fallback path handles deg>=MAXD

// ---- workspace layout (float offsets) ----
#define H_OFF     0                // h: N*256   (reused as agg after GAT)
#define OUT_OFF   12800000         // out: N*256
#define AS_OFF    25600000         // a_s: N*8
#define AD_OFF    26000000         // a_d: N*8
#define ROW_OFF   26400000         // int row[N+1]
#define DEG_OFF   26450016         // int deg[N]  (reused as fill cursor) [zero-init]
#define CSR_OFF   26500016         // int csr_src[N_EDGES]
#define POOL_OFF  27300016         // pooled sums 64*32 [zero-init]
#define CNT_OFF   27302064         // counts 64        [zero-init]
#define WS_END    27302128
#define AGG_OFF   H_OFF

__global__ __launch_bounds__(256) void k_zero(float* __restrict__ p, int n4) {
    int i = blockIdx.x * 256 + threadIdx.x;
    if (i < n4) ((float4*)p)[i] = make_float4(0.f, 0.f, 0.f, 0.f);
}

// h = x @ W_gat   (50000x128 @ 128x256), 16 nodes per block
__global__ __launch_bounds__(256) void k_gemm_h(const float* __restrict__ x,
                                                const float* __restrict__ Wg,
                                                float* __restrict__ h) {
    __shared__ float xs[16 * 128];
    int t = threadIdx.x;
    int n0 = blockIdx.x * 16;
#pragma unroll
    for (int r = 0; r < 8; ++r) {
        int idx = t + r * 256;
        xs[idx] = x[n0 * 128 + idx];
    }
    __syncthreads();
    float acc[16];
#pragma unroll
    for (int i = 0; i < 16; ++i) acc[i] = 0.f;
    for (int k = 0; k < 128; k += 4) {
        float w0 = Wg[(k + 0) * 256 + t];
        float w1 = Wg[(k + 1) * 256 + t];
        float w2 = Wg[(k + 2) * 256 + t];
        float w3 = Wg[(k + 3) * 256 + t];
#pragma unroll
        for (int i = 0; i < 16; ++i) {
            float4 xv = *(const float4*)&xs[i * 128 + k];
            acc[i] = fmaf(xv.x, w0, acc[i]);
            acc[i] = fmaf(xv.y, w1, acc[i]);
            acc[i] = fmaf(xv.z, w2, acc[i]);
            acc[i] = fmaf(xv.w, w3, acc[i]);
        }
    }
#pragma unroll
    for (int i = 0; i < 16; ++i) h[(n0 + i) * 256 + t] = acc[i];
}

// a_s[n,h] / a_d[n,h] dot products; one thread per (node,head)
__global__ __launch_bounds__(256) void k_attn_coef(const float* __restrict__ h,
                                                   const float* __restrict__ att_s,
                                                   const float* __restrict__ att_d,
                                                   float* __restrict__ a_s,
                                                   float* __restrict__ a_d) {
    int t = blockIdx.x * 256 + threadIdx.x;
    if (t >= N_NODES * HEADS) return;
    int n = t >> 3, hd = t & 7;
    const float* hp = h + n * HC + hd * HID;
    const float* sp = att_s + hd * HID;
    const float* dp = att_d + hd * HID;
    float as = 0.f, ad = 0.f;
#pragma unroll
    for (int c = 0; c < HID; c += 4) {
        float4 hv = *(const float4*)(hp + c);
        float4 sv = *(const float4*)(sp + c);
        float4 dv = *(const float4*)(dp + c);
        as += hv.x * sv.x + hv.y * sv.y + hv.z * sv.z + hv.w * sv.w;
        ad += hv.x * dv.x + hv.y * dv.y + hv.z * dv.z + hv.w * dv.w;
    }
    a_s[t] = as;
    a_d[t] = ad;
}

// ---------- CSR build ----------
__global__ __launch_bounds__(256) void k_hist(const int* __restrict__ ei,
                                              int* __restrict__ deg) {
    int e = blockIdx.x * 256 + threadIdx.x;
    if (e < N_EDGES) atomicAdd(&deg[ei[N_EDGES + e]], 1);
}

// single-block exclusive scan of deg[0..N) -> row[0..N]; zeroes deg for reuse
__global__ __launch_bounds__(1024) void k_scan(int* __restrict__ deg,
                                               int* __restrict__ row) {
    __shared__ int part[1024];
    int t = threadIdx.x;
    const int CH = (N_NODES + 1023) / 1024;  // 49
    int beg = t * CH;
    int end = beg + CH; if (end > N_NODES) end = N_NODES;
    int s = 0;
    for (int i = beg; i < end; ++i) s += deg[i];
    part[t] = s;
    __syncthreads();
    int v = s;
    for (int off = 1; off < 1024; off <<= 1) {
        int u = (t >= off) ? part[t - off] : 0;
        __syncthreads();
        v += u;
        part[t] = v;
        __syncthreads();
    }
    int run = v - s;  // exclusive prefix
    for (int i = beg; i < end; ++i) {
        int d = deg[i];
        row[i] = run;
        run += d;
        deg[i] = 0;
    }
    if (t == 1023) row[N_NODES] = run;
}

__global__ __launch_bounds__(256) void k_scatter(const int* __restrict__ ei,
                                                 const int* __restrict__ row,
                                                 int* __restrict__ fill,
                                                 int* __restrict__ csr) {
    int e = blockIdx.x * 256 + threadIdx.x;
    if (e >= N_EDGES) return;
    int d = ei[N_EDGES + e];
    int pos = row[d] + atomicAdd(&fill[d], 1);
    csr[pos] = ei[e];
}

// ---------- fused GAT: per-dst softmax + gather-aggregate + bias + relu ----------
// 4 nodes per block, one 64-lane wave per node.
__global__ __launch_bounds__(256) void k_gat(const int* __restrict__ row,
                                             const int* __restrict__ csr,
                                             const float* __restrict__ a_s,
                                             const float* __restrict__ a_d,
                                             const float* __restrict__ h,
                                             const float* __restrict__ bg,
                                             float* __restrict__ out) {
    __shared__ int   s_src[4][MAXD];
    __shared__ float s_es[4][MAXD * 8];
    int g = threadIdx.x >> 6;
    int lane = threadIdx.x & 63;
    int n = blockIdx.x * 4 + g;            // N_NODES % 4 == 0
    int r0 = row[n], r1 = row[n + 1];
    int deg = r1 - r0;
    int E = deg + 1;                       // + implicit self loop
    bool cached = (E <= MAXD);
    if (cached) {
        for (int j = lane; j < deg; j += 64) s_src[g][j] = csr[r0 + j];
    }
    __syncthreads();

    int hd = lane & 7, jl = lane >> 3;     // 8 edge-lanes x 8 heads
    float ad = a_d[n * 8 + hd];
    float pmax = -1e30f;
    for (int j = jl; j < E; j += 8) {
        int sj = (j < deg) ? (cached ? s_src[g][j] : csr[r0 + j]) : n;
        float v = a_s[sj * 8 + hd] + ad;
        v = v > 0.f ? v : 0.2f * v;
        if (cached) s_es[g][j * 8 + hd] = v;
        pmax = fmaxf(pmax, v);
    }
#pragma unroll
    for (int mask = 8; mask <= 32; mask <<= 1)
        pmax = fmaxf(pmax, __shfl_xor(pmax, mask, 64));
    float psum = 0.f;
    for (int j = jl; j < E; j += 8) {
        float v;
        if (cached) v = s_es[g][j * 8 + hd];
        else {
            int sj = (j < deg) ? csr[r0 + j] : n;
            v = a_s[sj * 8 + hd] + ad;
            v = v > 0.f ? v : 0.2f * v;
        }
        psum += __expf(v - pmax);
    }
#pragma unroll
    for (int mask = 8; mask <= 32; mask <<= 1)
        psum += __shfl_xor(psum, mask, 64);
    float invden = 1.0f / psum;
    if (cached) {
        for (int j = jl; j < E; j += 8)
            s_es[g][j * 8 + hd] = __expf(s_es[g][j * 8 + hd] - pmax) * invden;
    }
    __syncthreads();

    // phase 2: lane owns channels [lane*4, lane*4+4), head hd2 = lane>>3
    int hd2 = lane >> 3;
    float m2 = __shfl(pmax, hd2, 64);      // lane hd2 holds head-hd2 stats
    float inv2 = __shfl(invden, hd2, 64);
    float ad2 = a_d[n * 8 + hd2];
    float4 acc = make_float4(0.f, 0.f, 0.f, 0.f);
    for (int j = 0; j < E; ++j) {
        int sj = (j < deg) ? (cached ? s_src[g][j] : csr[r0 + j]) : n;
        float alpha;
        if (cached) {
            alpha = s_es[g][j * 8 + hd2];
        } else {
            float v = a_s[sj * 8 + hd2] + ad2;
            v = v > 0.f ? v : 0.2f * v;
            alpha = __expf(v - m2) * inv2;
        }
        float4 hv = *(const float4*)(h + sj * HC + lane * 4);
        acc.x = fmaf(alpha, hv.x, acc.x);
        acc.y = fmaf(alpha, hv.y, acc.y);
        acc.z = fmaf(alpha, hv.z, acc.z);
        acc.w = fmaf(alpha, hv.w, acc.w);
    }
    float4 b = *(const float4*)(bg + lane * 4);
    acc.x = fmaxf(acc.x + b.x, 0.f);
    acc.y = fmaxf(acc.y + b.y, 0.f);
    acc.z = fmaxf(acc.z + b.z, 0.f);
    acc.w = fmaxf(acc.w + b.w, 0.f);
    *(float4*)(out + n * HC + lane * 4) = acc;
}

// ---------- GIN gather: agg[n] = out[n] + sum_{j in in(n)} out[src_j] ----------
__global__ __launch_bounds__(256) void k_gin_gather(const int* __restrict__ row,
                                                    const int* __restrict__ csr,
                                                    const float* __restrict__ out,
                                                    float* __restrict__ agg) {
    int g = threadIdx.x >> 6;
    int lane = threadIdx.x & 63;
    int n = blockIdx.x * 4 + g;
    int r0 = row[n], r1 = row[n + 1];
    float4 acc = *(const float4*)(out + n * HC + lane * 4);
    for (int j = r0; j < r1; ++j) {
        int sj = csr[j];
        float4 v = *(const float4*)(out + sj * HC + lane * 4);
        acc.x += v.x; acc.y += v.y; acc.z += v.z; acc.w += v.w;
    }
    *(float4*)(agg + n * HC + lane * 4) = acc;
}

__global__ __launch_bounds__(256) void k_count(const int* __restrict__ batch,
                                               float* __restrict__ cnt) {
    int n = blockIdx.x * 256 + threadIdx.x;
    if (n >= N_NODES) return;
    atomicAdd(&cnt[batch[n]], 1.0f);
}

// z = relu(relu(agg@W1+b1)@W2+b2); pooled[batch[n]] += z. 8 nodes/block.
__global__ __launch_bounds__(256) void k_mlp_pool(const float* __restrict__ agg,
                                                  const int* __restrict__ batch,
                                                  const float* __restrict__ W1,
                                                  const float* __restrict__ b1,
                                                  const float* __restrict__ W2,
                                                  const float* __restrict__ b2,
                                                  float* __restrict__ pooled) {
    __shared__ float W1s[256 * 32];
    __shared__ float W2s[32 * 32];
    __shared__ float aggt[8 * 256];
    __shared__ float z1s[8 * 32];
    int t = threadIdx.x;
    int n0 = blockIdx.x * 8;
#pragma unroll
    for (int r = 0; r < 8; ++r)
        ((float4*)W1s)[t + r * 256] = ((const float4*)W1)[t + r * 256];
    ((float4*)W2s)[t] = ((const float4*)W2)[t];
#pragma unroll
    for (int r = 0; r < 2; ++r)
        ((float4*)aggt)[t + r * 256] = ((const float4*)(agg + n0 * HC))[t + r * 256];
    __syncthreads();
    int node = t >> 5, col = t & 31;
    float acc = b1[col];
    const float* ar = aggt + node * 256;
    for (int k = 0; k < 256; k += 4) {
        float4 av = *(const float4*)(ar + k);
        acc = fmaf(av.x, W1s[(k + 0) * 32 + col], acc);
        acc = fmaf(av.y, W1s[(k + 1) * 32 + col], acc);
        acc = fmaf(av.z, W1s[(k + 2) * 32 + col], acc);
        acc = fmaf(av.w, W1s[(k + 3) * 32 + col], acc);
    }
    z1s[node * 32 + col] = fmaxf(acc, 0.f);
    __syncthreads();
    float acc2 = b2[col];
    const float* zr = z1s + node * 32;
#pragma unroll
    for (int k = 0; k < 32; k += 4) {
        float4 zv = *(const float4*)(zr + k);
        acc2 = fmaf(zv.x, W2s[(k + 0) * 32 + col], acc2);
        acc2 = fmaf(zv.y, W2s[(k + 1) * 32 + col], acc2);
        acc2 = fmaf(zv.z, W2s[(k + 2) * 32 + col], acc2);
        acc2 = fmaf(zv.w, W2s[(k + 3) * 32 + col], acc2);
    }
    acc2 = fmaxf(acc2, 0.f);
    int g = batch[n0 + node];
    atomicAdd(&pooled[g * 32 + col], acc2);
}

__global__ __launch_bounds__(128) void k_final(const float* __restrict__ pooled,
                                               const float* __restrict__ cnt,
                                               const float* __restrict__ Wf,
                                               const float* __restrict__ bf,
                                               float* __restrict__ outp) {
    int g = blockIdx.x, c = threadIdx.x;
    float inv = 1.0f / fmaxf(cnt[g], 1.0f);
    float acc = 0.f;
#pragma unroll
    for (int k = 0; k < 32; ++k)
        acc = fmaf(pooled[g * 32 + k], Wf[k * 128 + c], acc);
    outp[g * 128 + c] = acc * inv + bf[c];
}

extern "C" void kernel_launch(void* const* d_in, const int* in_sizes, int n_in,
                              void* d_out, int out_size, void* d_ws, size_t ws_size,
                              hipStream_t stream) {
    const float* x     = (const float*)d_in[0];
    const int*   ei    = (const int*)d_in[1];
    const int*   batch = (const int*)d_in[2];
    const float* Wg    = (const float*)d_in[3];
    const float* att_s = (const float*)d_in[4];
    const float* att_d = (const float*)d_in[5];
    const float* bg    = (const float*)d_in[6];
    const float* W1    = (const float*)d_in[7];
    const float* b1    = (const float*)d_in[8];
    const float* W2    = (const float*)d_in[9];
    const float* b2    = (const float*)d_in[10];
    const float* Wf    = (const float*)d_in[11];
    const float* bf    = (const float*)d_in[12];
    float* ws = (float*)d_ws;

    float* h      = ws + H_OFF;
    float* out    = ws + OUT_OFF;
    float* a_s    = ws + AS_OFF;
    float* a_d    = ws + AD_OFF;
    int*   row    = (int*)(ws + ROW_OFF);
    int*   deg    = (int*)(ws + DEG_OFF);   // also scatter cursor
    int*   csr    = (int*)(ws + CSR_OFF);
    float* pooled = ws + POOL_OFF;
    float* cnt    = ws + CNT_OFF;
    float* agg    = ws + AGG_OFF;           // aliases h

    // zero: deg (50000 ints) and pooled+cnt (2112 floats)
    k_zero<<<(N_NODES / 4 + 255) / 256, 256, 0, stream>>>((float*)deg, N_NODES / 4);
    k_zero<<<((WS_END - POOL_OFF) / 4 + 255) / 256, 256, 0, stream>>>(pooled, (WS_END - POOL_OFF) / 4);

    // CSR build
    k_hist<<<(N_EDGES + 255) / 256, 256, 0, stream>>>(ei, deg);
    k_scan<<<1, 1024, 0, stream>>>(deg, row);
    k_scatter<<<(N_EDGES + 255) / 256, 256, 0, stream>>>(ei, row, deg, csr);

    // GAT
    k_gemm_h<<<N_NODES / 16, 256, 0, stream>>>(x, Wg, h);
    k_attn_coef<<<(N_NODES * HEADS + 255) / 256, 256, 0, stream>>>(h, att_s, att_d, a_s, a_d);
    k_gat<<<N_NODES / 4, 256, 0, stream>>>(row, csr, a_s, a_d, h, bg, out);

    // GIN (agg aliases h; h is dead after k_gat)
    k_gin_gather<<<N_NODES / 4, 256, 0, stream>>>(row, csr, out, agg);

    // MLP + pool + final
    k_count<<<(N_NODES + 255) / 256, 256, 0, stream>>>(batch, cnt);
    k_mlp_pool<<<N_NODES / 8, 256, 0, stream>>>(agg, batch, W1, b1, W2, b2, pooled);
    k_final<<<NG, 128, 0, stream>>>(pooled, cnt, Wf, bf, (float*)d_out);
}

// Round 3
// 723.593 us; speedup vs baseline: 9.2977x; 1.3567x over previous
//
#include <hip/hip_runtime.h>

#define N_NODES 50000
#define N_EDGES 800000
#define HEADS   8
#define HID     32
#define HC      256
#define NG      64
#define MAXD    128   // per-node LDS edge cache; fallback path handles deg>=MAXD

// ---- workspace layout (float offsets) ----
#define H_OFF     0                // h: N*256   (reused as agg after GAT)
#define OUT_OFF   12800000         // out: N*256 (reused as z (N*32) after GIN)
#define AS_OFF    25600000         // a_s: N*8
#define AD_OFF    26000000         // a_d: N*8
#define ROW_OFF   26400000         // int row[N+1]
#define DEG_OFF   26450016         // int deg[N]  (reused as fill cursor) [zero-init]
#define CSR_OFF   26500016         // int csr_src[N_EDGES]
#define GS_OFF    27300016         // int gstart[NG+1]
#define WS_END    27300088
#define AGG_OFF   H_OFF
#define Z_OFF     OUT_OFF

__global__ __launch_bounds__(256) void k_zero(float* __restrict__ p, int n4) {
    int i = blockIdx.x * 256 + threadIdx.x;
    if (i < n4) ((float4*)p)[i] = make_float4(0.f, 0.f, 0.f, 0.f);
}

// h = x @ W_gat   (50000x128 @ 128x256), 16 nodes per block
__global__ __launch_bounds__(256) void k_gemm_h(const float* __restrict__ x,
                                                const float* __restrict__ Wg,
                                                float* __restrict__ h) {
    __shared__ float xs[16 * 128];
    int t = threadIdx.x;
    int n0 = blockIdx.x * 16;
#pragma unroll
    for (int r = 0; r < 8; ++r) {
        int idx = t + r * 256;
        xs[idx] = x[n0 * 128 + idx];
    }
    __syncthreads();
    float acc[16];
#pragma unroll
    for (int i = 0; i < 16; ++i) acc[i] = 0.f;
    for (int k = 0; k < 128; k += 4) {
        float w0 = Wg[(k + 0) * 256 + t];
        float w1 = Wg[(k + 1) * 256 + t];
        float w2 = Wg[(k + 2) * 256 + t];
        float w3 = Wg[(k + 3) * 256 + t];
#pragma unroll
        for (int i = 0; i < 16; ++i) {
            float4 xv = *(const float4*)&xs[i * 128 + k];
            acc[i] = fmaf(xv.x, w0, acc[i]);
            acc[i] = fmaf(xv.y, w1, acc[i]);
            acc[i] = fmaf(xv.z, w2, acc[i]);
            acc[i] = fmaf(xv.w, w3, acc[i]);
        }
    }
#pragma unroll
    for (int i = 0; i < 16; ++i) h[(n0 + i) * 256 + t] = acc[i];
}

// a_s[n,h] / a_d[n,h] dot products; one thread per (node,head)
__global__ __launch_bounds__(256) void k_attn_coef(const float* __restrict__ h,
                                                   const float* __restrict__ att_s,
                                                   const float* __restrict__ att_d,
                                                   float* __restrict__ a_s,
                                                   float* __restrict__ a_d) {
    int t = blockIdx.x * 256 + threadIdx.x;
    if (t >= N_NODES * HEADS) return;
    int n = t >> 3, hd = t & 7;
    const float* hp = h + n * HC + hd * HID;
    const float* sp = att_s + hd * HID;
    const float* dp = att_d + hd * HID;
    float as = 0.f, ad = 0.f;
#pragma unroll
    for (int c = 0; c < HID; c += 4) {
        float4 hv = *(const float4*)(hp + c);
        float4 sv = *(const float4*)(sp + c);
        float4 dv = *(const float4*)(dp + c);
        as += hv.x * sv.x + hv.y * sv.y + hv.z * sv.z + hv.w * sv.w;
        ad += hv.x * dv.x + hv.y * dv.y + hv.z * dv.z + hv.w * dv.w;
    }
    a_s[t] = as;
    a_d[t] = ad;
}

// ---------- CSR build ----------
__global__ __launch_bounds__(256) void k_hist(const int* __restrict__ ei,
                                              int* __restrict__ deg) {
    int e = blockIdx.x * 256 + threadIdx.x;
    if (e < N_EDGES) atomicAdd(&deg[ei[N_EDGES + e]], 1);
}

// single-block exclusive scan of deg[0..N) -> row[0..N]; zeroes deg for reuse
__global__ __launch_bounds__(1024) void k_scan(int* __restrict__ deg,
                                               int* __restrict__ row) {
    __shared__ int part[1024];
    int t = threadIdx.x;
    const int CH = (N_NODES + 1023) / 1024;  // 49
    int beg = t * CH;
    int end = beg + CH; if (end > N_NODES) end = N_NODES;
    int s = 0;
    for (int i = beg; i < end; ++i) s += deg[i];
    part[t] = s;
    __syncthreads();
    int v = s;
    for (int off = 1; off < 1024; off <<= 1) {
        int u = (t >= off) ? part[t - off] : 0;
        __syncthreads();
        v += u;
        part[t] = v;
        __syncthreads();
    }
    int run = v - s;  // exclusive prefix
    for (int i = beg; i < end; ++i) {
        int d = deg[i];
        row[i] = run;
        run += d;
        deg[i] = 0;
    }
    if (t == 1023) row[N_NODES] = run;
}

__global__ __launch_bounds__(256) void k_scatter(const int* __restrict__ ei,
                                                 const int* __restrict__ row,
                                                 int* __restrict__ fill,
                                                 int* __restrict__ csr) {
    int e = blockIdx.x * 256 + threadIdx.x;
    if (e >= N_EDGES) return;
    int d = ei[N_EDGES + e];
    int pos = row[d] + atomicAdd(&fill[d], 1);
    csr[pos] = ei[e];
}

// graph segment boundaries in sorted batch: gs[g] = lower_bound(batch, g)
__global__ __launch_bounds__(128) void k_bounds(const int* __restrict__ batch,
                                                int* __restrict__ gs) {
    int g = threadIdx.x;
    if (g > NG) return;
    int lo = 0, hi = N_NODES;
    while (lo < hi) {
        int mid = (lo + hi) >> 1;
        if (batch[mid] < g) lo = mid + 1; else hi = mid;
    }
    gs[g] = lo;
}

// ---------- fused GAT: per-dst softmax + gather-aggregate + bias + relu ----------
// 4 nodes per block, one 64-lane wave per node.
__global__ __launch_bounds__(256) void k_gat(const int* __restrict__ row,
                                             const int* __restrict__ csr,
                                             const float* __restrict__ a_s,
                                             const float* __restrict__ a_d,
                                             const float* __restrict__ h,
                                             const float* __restrict__ bg,
                                             float* __restrict__ out) {
    __shared__ int   s_src[4][MAXD];
    __shared__ float s_es[4][MAXD * 8];
    int g = threadIdx.x >> 6;
    int lane = threadIdx.x & 63;
    int n = blockIdx.x * 4 + g;            // N_NODES % 4 == 0
    int r0 = row[n], r1 = row[n + 1];
    int deg = r1 - r0;
    int E = deg + 1;                       // + implicit self loop
    bool cached = (E <= MAXD);
    if (cached) {
        for (int j = lane; j < deg; j += 64) s_src[g][j] = csr[r0 + j];
    }
    __syncthreads();

    int hd = lane & 7, jl = lane >> 3;     // 8 edge-lanes x 8 heads
    float ad = a_d[n * 8 + hd];
    float pmax = -1e30f;
    for (int j = jl; j < E; j += 8) {
        int sj = (j < deg) ? (cached ? s_src[g][j] : csr[r0 + j]) : n;
        float v = a_s[sj * 8 + hd] + ad;
        v = v > 0.f ? v : 0.2f * v;
        if (cached) s_es[g][j * 8 + hd] = v;
        pmax = fmaxf(pmax, v);
    }
#pragma unroll
    for (int mask = 8; mask <= 32; mask <<= 1)
        pmax = fmaxf(pmax, __shfl_xor(pmax, mask, 64));
    float psum = 0.f;
    for (int j = jl; j < E; j += 8) {
        float v;
        if (cached) v = s_es[g][j * 8 + hd];
        else {
            int sj = (j < deg) ? csr[r0 + j] : n;
            v = a_s[sj * 8 + hd] + ad;
            v = v > 0.f ? v : 0.2f * v;
        }
        psum += __expf(v - pmax);
    }
#pragma unroll
    for (int mask = 8; mask <= 32; mask <<= 1)
        psum += __shfl_xor(psum, mask, 64);
    float invden = 1.0f / psum;
    if (cached) {
        for (int j = jl; j < E; j += 8)
            s_es[g][j * 8 + hd] = __expf(s_es[g][j * 8 + hd] - pmax) * invden;
    }
    __syncthreads();

    // phase 2: lane owns channels [lane*4, lane*4+4), head hd2 = lane>>3
    int hd2 = lane >> 3;
    float m2 = __shfl(pmax, hd2, 64);      // lane hd2 holds head-hd2 stats
    float inv2 = __shfl(invden, hd2, 64);
    float ad2 = a_d[n * 8 + hd2];
    float4 acc = make_float4(0.f, 0.f, 0.f, 0.f);
    for (int j = 0; j < E; ++j) {
        int sj = (j < deg) ? (cached ? s_src[g][j] : csr[r0 + j]) : n;
        float alpha;
        if (cached) {
            alpha = s_es[g][j * 8 + hd2];
        } else {
            float v = a_s[sj * 8 + hd2] + ad2;
            v = v > 0.f ? v : 0.2f * v;
            alpha = __expf(v - m2) * inv2;
        }
        float4 hv = *(const float4*)(h + sj * HC + lane * 4);
        acc.x = fmaf(alpha, hv.x, acc.x);
        acc.y = fmaf(alpha, hv.y, acc.y);
        acc.z = fmaf(alpha, hv.z, acc.z);
        acc.w = fmaf(alpha, hv.w, acc.w);
    }
    float4 b = *(const float4*)(bg + lane * 4);
    acc.x = fmaxf(acc.x + b.x, 0.f);
    acc.y = fmaxf(acc.y + b.y, 0.f);
    acc.z = fmaxf(acc.z + b.z, 0.f);
    acc.w = fmaxf(acc.w + b.w, 0.f);
    *(float4*)(out + n * HC + lane * 4) = acc;
}

// ---------- GIN gather: agg[n] = out[n] + sum_{j in in(n)} out[src_j] ----------
__global__ __launch_bounds__(256) void k_gin_gather(const int* __restrict__ row,
                                                    const int* __restrict__ csr,
                                                    const float* __restrict__ out,
                                                    float* __restrict__ agg) {
    int g = threadIdx.x >> 6;
    int lane = threadIdx.x & 63;
    int n = blockIdx.x * 4 + g;
    int r0 = row[n], r1 = row[n + 1];
    float4 acc = *(const float4*)(out + n * HC + lane * 4);
    for (int j = r0; j < r1; ++j) {
        int sj = csr[j];
        float4 v = *(const float4*)(out + sj * HC + lane * 4);
        acc.x += v.x; acc.y += v.y; acc.z += v.z; acc.w += v.w;
    }
    *(float4*)(agg + n * HC + lane * 4) = acc;
}

// z = relu(relu(agg@W1+b1)@W2+b2), dense write, no atomics. 8 nodes/block.
__global__ __launch_bounds__(256) void k_mlp(const float* __restrict__ agg,
                                             const float* __restrict__ W1,
                                             const float* __restrict__ b1,
                                             const float* __restrict__ W2,
                                             const float* __restrict__ b2,
                                             float* __restrict__ z) {
    __shared__ float W1s[256 * 32];
    __shared__ float W2s[32 * 32];
    __shared__ float aggt[8 * 256];
    __shared__ float z1s[8 * 32];
    int t = threadIdx.x;
    int n0 = blockIdx.x * 8;
#pragma unroll
    for (int r = 0; r < 8; ++r)
        ((float4*)W1s)[t + r * 256] = ((const float4*)W1)[t + r * 256];
    ((float4*)W2s)[t] = ((const float4*)W2)[t];
#pragma unroll
    for (int r = 0; r < 2; ++r)
        ((float4*)aggt)[t + r * 256] = ((const float4*)(agg + n0 * HC))[t + r * 256];
    __syncthreads();
    int node = t >> 5, col = t & 31;
    float acc = b1[col];
    const float* ar = aggt + node * 256;
    for (int k = 0; k < 256; k += 4) {
        float4 av = *(const float4*)(ar + k);
        acc = fmaf(av.x, W1s[(k + 0) * 32 + col], acc);
        acc = fmaf(av.y, W1s[(k + 1) * 32 + col], acc);
        acc = fmaf(av.z, W1s[(k + 2) * 32 + col], acc);
        acc = fmaf(av.w, W1s[(k + 3) * 32 + col], acc);
    }
    z1s[node * 32 + col] = fmaxf(acc, 0.f);
    __syncthreads();
    float acc2 = b2[col];
    const float* zr = z1s + node * 32;
#pragma unroll
    for (int k = 0; k < 32; k += 4) {
        float4 zv = *(const float4*)(zr + k);
        acc2 = fmaf(zv.x, W2s[(k + 0) * 32 + col], acc2);
        acc2 = fmaf(zv.y, W2s[(k + 1) * 32 + col], acc2);
        acc2 = fmaf(zv.z, W2s[(k + 2) * 32 + col], acc2);
        acc2 = fmaf(zv.w, W2s[(k + 3) * 32 + col], acc2);
    }
    z[(n0 + node) * 32 + col] = fmaxf(acc2, 0.f);
}

// one block per graph: mean-pool its contiguous z rows, then @Wf + bf
__global__ __launch_bounds__(128) void k_pool_final(const float* __restrict__ z,
                                                    const int* __restrict__ gs,
                                                    const float* __restrict__ Wf,
                                                    const float* __restrict__ bf,
                                                    float* __restrict__ outp) {
    __shared__ float part[4][32];
    __shared__ float sums[32];
    int g = blockIdx.x;
    int t = threadIdx.x;
    int col = t & 31, q = t >> 5;
    int r0 = gs[g], r1 = gs[g + 1];
    float s = 0.f;
    for (int r = r0 + q; r < r1; r += 4) s += z[r * 32 + col];
    part[q][col] = s;
    __syncthreads();
    if (t < 32) sums[t] = part[0][t] + part[1][t] + part[2][t] + part[3][t];
    __syncthreads();
    float inv = 1.0f / fmaxf((float)(r1 - r0), 1.0f);
    float acc = 0.f;
#pragma unroll
    for (int k = 0; k < 32; ++k)
        acc = fmaf(sums[k], Wf[k * 128 + t], acc);
    outp[g * 128 + t] = acc * inv + bf[t];
}

extern "C" void kernel_launch(void* const* d_in, const int* in_sizes, int n_in,
                              void* d_out, int out_size, void* d_ws, size_t ws_size,
                              hipStream_t stream) {
    const float* x     = (const float*)d_in[0];
    const int*   ei    = (const int*)d_in[1];
    const int*   batch = (const int*)d_in[2];
    const float* Wg    = (const float*)d_in[3];
    const float* att_s = (const float*)d_in[4];
    const float* att_d = (const float*)d_in[5];
    const float* bg    = (const float*)d_in[6];
    const float* W1    = (const float*)d_in[7];
    const float* b1    = (const float*)d_in[8];
    const float* W2    = (const float*)d_in[9];
    const float* b2    = (const float*)d_in[10];
    const float* Wf    = (const float*)d_in[11];
    const float* bf    = (const float*)d_in[12];
    float* ws = (float*)d_ws;

    float* h      = ws + H_OFF;
    float* out    = ws + OUT_OFF;
    float* a_s    = ws + AS_OFF;
    float* a_d    = ws + AD_OFF;
    int*   row    = (int*)(ws + ROW_OFF);
    int*   deg    = (int*)(ws + DEG_OFF);   // also scatter cursor
    int*   csr    = (int*)(ws + CSR_OFF);
    int*   gs     = (int*)(ws + GS_OFF);
    float* agg    = ws + AGG_OFF;           // aliases h
    float* z      = ws + Z_OFF;             // aliases out (dead after GIN)

    // zero: deg (50000 ints)
    k_zero<<<(N_NODES / 4 + 255) / 256, 256, 0, stream>>>((float*)deg, N_NODES / 4);

    // CSR build + graph bounds
    k_hist<<<(N_EDGES + 255) / 256, 256, 0, stream>>>(ei, deg);
    k_scan<<<1, 1024, 0, stream>>>(deg, row);
    k_scatter<<<(N_EDGES + 255) / 256, 256, 0, stream>>>(ei, row, deg, csr);
    k_bounds<<<1, 128, 0, stream>>>(batch, gs);

    // GAT
    k_gemm_h<<<N_NODES / 16, 256, 0, stream>>>(x, Wg, h);
    k_attn_coef<<<(N_NODES * HEADS + 255) / 256, 256, 0, stream>>>(h, att_s, att_d, a_s, a_d);
    k_gat<<<N_NODES / 4, 256, 0, stream>>>(row, csr, a_s, a_d, h, bg, out);

    // GIN (agg aliases h; h is dead after k_gat)
    k_gin_gather<<<N_NODES / 4, 256, 0, stream>>>(row, csr, out, agg);

    // MLP -> z (aliases out), then per-graph pool + final linear
    k_mlp<<<N_NODES / 8, 256, 0, stream>>>(agg, W1, b1, W2, b2, z);
    k_pool_final<<<NG, 128, 0, stream>>>(z, gs, Wf, bf, (float*)d_out);
}

// Round 4
// 650.710 us; speedup vs baseline: 10.3391x; 1.1120x over previous
//
#include <hip/hip_runtime.h>

#define N_NODES 50000
#define N_EDGES 800000
#define HEADS   8
#define HID     32
#define HC      256
#define NG      64
#define MAXD    128   // per-node LDS edge cache; fallback path handles deg>=MAXD

typedef unsigned short ushort_t;
typedef unsigned int   uint_t;

// ---- workspace layout (float offsets) ----
// hb (bf16 h, N*256 ushort = 25.6MB) occupies the front of the agg region;
// hb is dead after k_gat, then k_gin writes agg (fp32 N*256) over it.
#define AGG_OFF   0
#define HB_OFF    0
#define OUTB_OFF  12800000         // out bf16: N*256 ushort (25.6MB = 6.4M floats)
#define Z_OFF     OUTB_OFF         // z fp32 N*32 aliases out_bf (dead after GIN)
#define AS_OFF    19200000         // a_s: N*8 fp32
#define AD_OFF    19600000         // a_d: N*8 fp32
#define ROW_OFF   20000000         // int row[N+1]
#define DEG_OFF   20050016         // int deg[N] (reused as fill cursor) [zero-init]
#define CSR_OFF   20100016         // int csr_src[N_EDGES]
#define GS_OFF    20900016         // int gstart[NG+1]
#define WS_END    20900084

__device__ __forceinline__ ushort_t f2bf(float f) {
    uint_t u = __float_as_uint(f);
    u = (u + 0x7FFFu + ((u >> 16) & 1u)) >> 16;   // RNE
    return (ushort_t)u;
}
__device__ __forceinline__ float bf_lo(uint_t u) { return __uint_as_float(u << 16); }
__device__ __forceinline__ float bf_hi(uint_t u) { return __uint_as_float(u & 0xFFFF0000u); }

__global__ __launch_bounds__(256) void k_zero(float* __restrict__ p, int n4) {
    int i = blockIdx.x * 256 + threadIdx.x;
    if (i < n4) ((float4*)p)[i] = make_float4(0.f, 0.f, 0.f, 0.f);
}

// hb = bf16(x @ W_gat)   (50000x128 @ 128x256), 16 nodes per block
__global__ __launch_bounds__(256) void k_gemm_h(const float* __restrict__ x,
                                                const float* __restrict__ Wg,
                                                ushort_t* __restrict__ hb) {
    __shared__ float xs[16 * 128];
    int t = threadIdx.x;
    int n0 = blockIdx.x * 16;
#pragma unroll
    for (int r = 0; r < 8; ++r) {
        int idx = t + r * 256;
        xs[idx] = x[n0 * 128 + idx];
    }
    __syncthreads();
    float acc[16];
#pragma unroll
    for (int i = 0; i < 16; ++i) acc[i] = 0.f;
    for (int k = 0; k < 128; k += 4) {
        float w0 = Wg[(k + 0) * 256 + t];
        float w1 = Wg[(k + 1) * 256 + t];
        float w2 = Wg[(k + 2) * 256 + t];
        float w3 = Wg[(k + 3) * 256 + t];
#pragma unroll
        for (int i = 0; i < 16; ++i) {
            float4 xv = *(const float4*)&xs[i * 128 + k];
            acc[i] = fmaf(xv.x, w0, acc[i]);
            acc[i] = fmaf(xv.y, w1, acc[i]);
            acc[i] = fmaf(xv.z, w2, acc[i]);
            acc[i] = fmaf(xv.w, w3, acc[i]);
        }
    }
#pragma unroll
    for (int i = 0; i < 16; ++i) hb[(n0 + i) * 256 + t] = f2bf(acc[i]);
}

// a_s[n,h] / a_d[n,h] dot products from bf16 h; one thread per (node,head)
__global__ __launch_bounds__(256) void k_attn_coef(const ushort_t* __restrict__ hb,
                                                   const float* __restrict__ att_s,
                                                   const float* __restrict__ att_d,
                                                   float* __restrict__ a_s,
                                                   float* __restrict__ a_d) {
    int t = blockIdx.x * 256 + threadIdx.x;
    if (t >= N_NODES * HEADS) return;
    int n = t >> 3, hd = t & 7;
    const ushort_t* hp = hb + n * HC + hd * HID;
    const float* sp = att_s + hd * HID;
    const float* dp = att_d + hd * HID;
    float as = 0.f, ad = 0.f;
#pragma unroll
    for (int c = 0; c < HID; c += 8) {
        uint4 u = *(const uint4*)(hp + c);   // 8 bf16
        float h0 = bf_lo(u.x), h1 = bf_hi(u.x);
        float h2 = bf_lo(u.y), h3 = bf_hi(u.y);
        float h4 = bf_lo(u.z), h5 = bf_hi(u.z);
        float h6 = bf_lo(u.w), h7 = bf_hi(u.w);
        float4 s0 = *(const float4*)(sp + c);
        float4 s1 = *(const float4*)(sp + c + 4);
        float4 d0 = *(const float4*)(dp + c);
        float4 d1 = *(const float4*)(dp + c + 4);
        as += h0 * s0.x + h1 * s0.y + h2 * s0.z + h3 * s0.w
            + h4 * s1.x + h5 * s1.y + h6 * s1.z + h7 * s1.w;
        ad += h0 * d0.x + h1 * d0.y + h2 * d0.z + h3 * d0.w
            + h4 * d1.x + h5 * d1.y + h6 * d1.z + h7 * d1.w;
    }
    a_s[t] = as;
    a_d[t] = ad;
}

// ---------- CSR build ----------
__global__ __launch_bounds__(256) void k_hist(const int* __restrict__ ei,
                                              int* __restrict__ deg) {
    int e = blockIdx.x * 256 + threadIdx.x;
    if (e < N_EDGES) atomicAdd(&deg[ei[N_EDGES + e]], 1);
}

__global__ __launch_bounds__(1024) void k_scan(int* __restrict__ deg,
                                               int* __restrict__ row) {
    __shared__ int part[1024];
    int t = threadIdx.x;
    const int CH = (N_NODES + 1023) / 1024;  // 49
    int beg = t * CH;
    int end = beg + CH; if (end > N_NODES) end = N_NODES;
    int s = 0;
    for (int i = beg; i < end; ++i) s += deg[i];
    part[t] = s;
    __syncthreads();
    int v = s;
    for (int off = 1; off < 1024; off <<= 1) {
        int u = (t >= off) ? part[t - off] : 0;
        __syncthreads();
        v += u;
        part[t] = v;
        __syncthreads();
    }
    int run = v - s;  // exclusive prefix
    for (int i = beg; i < end; ++i) {
        int d = deg[i];
        row[i] = run;
        run += d;
        deg[i] = 0;
    }
    if (t == 1023) row[N_NODES] = run;
}

__global__ __launch_bounds__(256) void k_scatter(const int* __restrict__ ei,
                                                 const int* __restrict__ row,
                                                 int* __restrict__ fill,
                                                 int* __restrict__ csr) {
    int e = blockIdx.x * 256 + threadIdx.x;
    if (e >= N_EDGES) return;
    int d = ei[N_EDGES + e];
    int pos = row[d] + atomicAdd(&fill[d], 1);
    csr[pos] = ei[e];
}

// graph segment boundaries in sorted batch
__global__ __launch_bounds__(128) void k_bounds(const int* __restrict__ batch,
                                                int* __restrict__ gs) {
    int g = threadIdx.x;
    if (g > NG) return;
    int lo = 0, hi = N_NODES;
    while (lo < hi) {
        int mid = (lo + hi) >> 1;
        if (batch[mid] < g) lo = mid + 1; else hi = mid;
    }
    gs[g] = lo;
}

// ---------- fused GAT: per-dst softmax + bf16 gather-aggregate + bias + relu ----------
__global__ __launch_bounds__(256) void k_gat(const int* __restrict__ row,
                                             const int* __restrict__ csr,
                                             const float* __restrict__ a_s,
                                             const float* __restrict__ a_d,
                                             const ushort_t* __restrict__ hb,
                                             const float* __restrict__ bg,
                                             ushort_t* __restrict__ outb) {
    __shared__ int   s_src[4][MAXD];
    __shared__ float s_es[4][MAXD * 8];
    int g = threadIdx.x >> 6;
    int lane = threadIdx.x & 63;
    int n = blockIdx.x * 4 + g;            // N_NODES % 4 == 0
    int r0 = row[n], r1 = row[n + 1];
    int deg = r1 - r0;
    int E = deg + 1;                       // + implicit self loop
    bool cached = (E <= MAXD);
    if (cached) {
        for (int j = lane; j < deg; j += 64) s_src[g][j] = csr[r0 + j];
    }
    __syncthreads();

    int hd = lane & 7, jl = lane >> 3;     // 8 edge-lanes x 8 heads
    float ad = a_d[n * 8 + hd];
    float pmax = -1e30f;
    for (int j = jl; j < E; j += 8) {
        int sj = (j < deg) ? (cached ? s_src[g][j] : csr[r0 + j]) : n;
        float v = a_s[sj * 8 + hd] + ad;
        v = v > 0.f ? v : 0.2f * v;
        if (cached) s_es[g][j * 8 + hd] = v;
        pmax = fmaxf(pmax, v);
    }
#pragma unroll
    for (int mask = 8; mask <= 32; mask <<= 1)
        pmax = fmaxf(pmax, __shfl_xor(pmax, mask, 64));
    float psum = 0.f;
    for (int j = jl; j < E; j += 8) {
        float v;
        if (cached) v = s_es[g][j * 8 + hd];
        else {
            int sj = (j < deg) ? csr[r0 + j] : n;
            v = a_s[sj * 8 + hd] + ad;
            v = v > 0.f ? v : 0.2f * v;
        }
        psum += __expf(v - pmax);
    }
#pragma unroll
    for (int mask = 8; mask <= 32; mask <<= 1)
        psum += __shfl_xor(psum, mask, 64);
    float invden = 1.0f / psum;
    if (cached) {
        for (int j = jl; j < E; j += 8)
            s_es[g][j * 8 + hd] = __expf(s_es[g][j * 8 + hd] - pmax) * invden;
    }
    __syncthreads();

    // phase 2: lane owns channels [lane*4, lane*4+4), head hd2 = lane>>3
    int hd2 = lane >> 3;
    float m2 = __shfl(pmax, hd2, 64);
    float inv2 = __shfl(invden, hd2, 64);
    float ad2 = a_d[n * 8 + hd2];
    float4 acc = make_float4(0.f, 0.f, 0.f, 0.f);
    for (int j = 0; j < E; ++j) {
        int sj = (j < deg) ? (cached ? s_src[g][j] : csr[r0 + j]) : n;
        float alpha;
        if (cached) {
            alpha = s_es[g][j * 8 + hd2];
        } else {
            float v = a_s[sj * 8 + hd2] + ad2;
            v = v > 0.f ? v : 0.2f * v;
            alpha = __expf(v - m2) * inv2;
        }
        uint2 u = *(const uint2*)(hb + sj * HC + lane * 4);  // 4 bf16
        acc.x = fmaf(alpha, bf_lo(u.x), acc.x);
        acc.y = fmaf(alpha, bf_hi(u.x), acc.y);
        acc.z = fmaf(alpha, bf_lo(u.y), acc.z);
        acc.w = fmaf(alpha, bf_hi(u.y), acc.w);
    }
    float4 b = *(const float4*)(bg + lane * 4);
    acc.x = fmaxf(acc.x + b.x, 0.f);
    acc.y = fmaxf(acc.y + b.y, 0.f);
    acc.z = fmaxf(acc.z + b.z, 0.f);
    acc.w = fmaxf(acc.w + b.w, 0.f);
    uint2 o;
    o.x = (uint_t)f2bf(acc.x) | ((uint_t)f2bf(acc.y) << 16);
    o.y = (uint_t)f2bf(acc.z) | ((uint_t)f2bf(acc.w) << 16);
    *(uint2*)(outb + n * HC + lane * 4) = o;
}

// ---------- GIN gather (bf16 in, fp32 agg out) ----------
__global__ __launch_bounds__(256) void k_gin_gather(const int* __restrict__ row,
                                                    const int* __restrict__ csr,
                                                    const ushort_t* __restrict__ outb,
                                                    float* __restrict__ agg) {
    int g = threadIdx.x >> 6;
    int lane = threadIdx.x & 63;
    int n = blockIdx.x * 4 + g;
    int r0 = row[n], r1 = row[n + 1];
    uint2 u = *(const uint2*)(outb + n * HC + lane * 4);
    float4 acc = make_float4(bf_lo(u.x), bf_hi(u.x), bf_lo(u.y), bf_hi(u.y));
    for (int j = r0; j < r1; ++j) {
        int sj = csr[j];
        uint2 v = *(const uint2*)(outb + sj * HC + lane * 4);
        acc.x += bf_lo(v.x); acc.y += bf_hi(v.x);
        acc.z += bf_lo(v.y); acc.w += bf_hi(v.y);
    }
    *(float4*)(agg + n * HC + lane * 4) = acc;
}

// z = relu(relu(agg@W1+b1)@W2+b2), dense write, no atomics. 8 nodes/block.
__global__ __launch_bounds__(256) void k_mlp(const float* __restrict__ agg,
                                             const float* __restrict__ W1,
                                             const float* __restrict__ b1,
                                             const float* __restrict__ W2,
                                             const float* __restrict__ b2,
                                             float* __restrict__ z) {
    __shared__ float W1s[256 * 32];
    __shared__ float W2s[32 * 32];
    __shared__ float aggt[8 * 256];
    __shared__ float z1s[8 * 32];
    int t = threadIdx.x;
    int n0 = blockIdx.x * 8;
#pragma unroll
    for (int r = 0; r < 8; ++r)
        ((float4*)W1s)[t + r * 256] = ((const float4*)W1)[t + r * 256];
    ((float4*)W2s)[t] = ((const float4*)W2)[t];
#pragma unroll
    for (int r = 0; r < 2; ++r)
        ((float4*)aggt)[t + r * 256] = ((const float4*)(agg + n0 * HC))[t + r * 256];
    __syncthreads();
    int node = t >> 5, col = t & 31;
    float acc = b1[col];
    const float* ar = aggt + node * 256;
    for (int k = 0; k < 256; k += 4) {
        float4 av = *(const float4*)(ar + k);
        acc = fmaf(av.x, W1s[(k + 0) * 32 + col], acc);
        acc = fmaf(av.y, W1s[(k + 1) * 32 + col], acc);
        acc = fmaf(av.z, W1s[(k + 2) * 32 + col], acc);
        acc = fmaf(av.w, W1s[(k + 3) * 32 + col], acc);
    }
    z1s[node * 32 + col] = fmaxf(acc, 0.f);
    __syncthreads();
    float acc2 = b2[col];
    const float* zr = z1s + node * 32;
#pragma unroll
    for (int k = 0; k < 32; k += 4) {
        float4 zv = *(const float4*)(zr + k);
        acc2 = fmaf(zv.x, W2s[(k + 0) * 32 + col], acc2);
        acc2 = fmaf(zv.y, W2s[(k + 1) * 32 + col], acc2);
        acc2 = fmaf(zv.z, W2s[(k + 2) * 32 + col], acc2);
        acc2 = fmaf(zv.w, W2s[(k + 3) * 32 + col], acc2);
    }
    z[(n0 + node) * 32 + col] = fmaxf(acc2, 0.f);
}

// one block per graph: mean-pool its contiguous z rows, then @Wf + bf
__global__ __launch_bounds__(128) void k_pool_final(const float* __restrict__ z,
                                                    const int* __restrict__ gs,
                                                    const float* __restrict__ Wf,
                                                    const float* __restrict__ bf,
                                                    float* __restrict__ outp) {
    __shared__ float part[4][32];
    __shared__ float sums[32];
    int g = blockIdx.x;
    int t = threadIdx.x;
    int col = t & 31, q = t >> 5;
    int r0 = gs[g], r1 = gs[g + 1];
    float s = 0.f;
    for (int r = r0 + q; r < r1; r += 4) s += z[r * 32 + col];
    part[q][col] = s;
    __syncthreads();
    if (t < 32) sums[t] = part[0][t] + part[1][t] + part[2][t] + part[3][t];
    __syncthreads();
    float inv = 1.0f / fmaxf((float)(r1 - r0), 1.0f);
    float acc = 0.f;
#pragma unroll
    for (int k = 0; k < 32; ++k)
        acc = fmaf(sums[k], Wf[k * 128 + t], acc);
    outp[g * 128 + t] = acc * inv + bf[t];
}

extern "C" void kernel_launch(void* const* d_in, const int* in_sizes, int n_in,
                              void* d_out, int out_size, void* d_ws, size_t ws_size,
                              hipStream_t stream) {
    const float* x     = (const float*)d_in[0];
    const int*   ei    = (const int*)d_in[1];
    const int*   batch = (const int*)d_in[2];
    const float* Wg    = (const float*)d_in[3];
    const float* att_s = (const float*)d_in[4];
    const float* att_d = (const float*)d_in[5];
    const float* bg    = (const float*)d_in[6];
    const float* W1    = (const float*)d_in[7];
    const float* b1    = (const float*)d_in[8];
    const float* W2    = (const float*)d_in[9];
    const float* b2    = (const float*)d_in[10];
    const float* Wf    = (const float*)d_in[11];
    const float* bf    = (const float*)d_in[12];
    float* ws = (float*)d_ws;

    ushort_t* hb   = (ushort_t*)(ws + HB_OFF);
    ushort_t* outb = (ushort_t*)(ws + OUTB_OFF);
    float* a_s    = ws + AS_OFF;
    float* a_d    = ws + AD_OFF;
    int*   row    = (int*)(ws + ROW_OFF);
    int*   deg    = (int*)(ws + DEG_OFF);
    int*   csr    = (int*)(ws + CSR_OFF);
    int*   gs     = (int*)(ws + GS_OFF);
    float* agg    = ws + AGG_OFF;           // overlays hb (hb dead after k_gat)
    float* z      = ws + Z_OFF;             // overlays outb (dead after GIN)

    // zero: deg (50000 ints)
    k_zero<<<(N_NODES / 4 + 255) / 256, 256, 0, stream>>>((float*)deg, N_NODES / 4);

    // CSR build + graph bounds
    k_hist<<<(N_EDGES + 255) / 256, 256, 0, stream>>>(ei, deg);
    k_scan<<<1, 1024, 0, stream>>>(deg, row);
    k_scatter<<<(N_EDGES + 255) / 256, 256, 0, stream>>>(ei, row, deg, csr);
    k_bounds<<<1, 128, 0, stream>>>(batch, gs);

    // GAT
    k_gemm_h<<<N_NODES / 16, 256, 0, stream>>>(x, Wg, hb);
    k_attn_coef<<<(N_NODES * HEADS + 255) / 256, 256, 0, stream>>>(hb, att_s, att_d, a_s, a_d);
    k_gat<<<N_NODES / 4, 256, 0, stream>>>(row, csr, a_s, a_d, hb, bg, outb);

    // GIN (agg overlays hb region; hb dead after k_gat)
    k_gin_gather<<<N_NODES / 4, 256, 0, stream>>>(row, csr, outb, agg);

    // MLP -> z (overlays outb), then per-graph pool + final linear
    k_mlp<<<N_NODES / 8, 256, 0, stream>>>(agg, W1, b1, W2, b2, z);
    k_pool_final<<<NG, 128, 0, stream>>>(z, gs, Wf, bf, (float*)d_out);
}

// Round 5
// 540.987 us; speedup vs baseline: 12.4361x; 1.2028x over previous
//
#include <hip/hip_runtime.h>

#define N_NODES 50000
#define N_EDGES 800000
#define HEADS   8
#define HID     32
#define HC      256
#define NG      64
#define MAXD    128   // per-node LDS edge cache; fallback path handles deg>=MAXD
#define SCAN_BLOCKS ((N_NODES + 255) / 256)   // 196

typedef unsigned short ushort_t;
typedef unsigned int   uint_t;

// ---- workspace layout (float offsets) ----
// hb (bf16 h, N*256 ushort = 25.6MB) occupies the front of the agg region;
// hb is dead after k_gat, then k_gin writes agg (fp32 N*256) over it.
#define AGG_OFF   0
#define HB_OFF    0
#define OUTB_OFF  12800000         // out bf16: N*256 ushort (25.6MB = 6.4M floats)
#define Z_OFF     OUTB_OFF         // z fp32 N*32 aliases out_bf (dead after GIN)
#define AS_OFF    19200000         // a_s: N*8 fp32
#define AD_OFF    19600000         // a_d: N*8 fp32
#define ROW_OFF   20000000         // int row[N+1]
#define DEG_OFF   20050016         // int deg[N] (reused as fill cursor) [zero-init]
#define CSR_OFF   20100016         // int csr_src[N_EDGES]
#define GS_OFF    20900016         // int gstart[NG+1]
#define BSUM_OFF  20900088         // int bsum[SCAN_BLOCKS]
#define WS_END    20900284

__device__ __forceinline__ ushort_t f2bf(float f) {
    uint_t u = __float_as_uint(f);
    u = (u + 0x7FFFu + ((u >> 16) & 1u)) >> 16;   // RNE
    return (ushort_t)u;
}
__device__ __forceinline__ float bf_lo(uint_t u) { return __uint_as_float(u << 16); }
__device__ __forceinline__ float bf_hi(uint_t u) { return __uint_as_float(u & 0xFFFF0000u); }

__global__ __launch_bounds__(256) void k_zero(float* __restrict__ p, int n4) {
    int i = blockIdx.x * 256 + threadIdx.x;
    if (i < n4) ((float4*)p)[i] = make_float4(0.f, 0.f, 0.f, 0.f);
}

// hb = bf16(x @ W_gat)   (50000x128 @ 128x256), 16 nodes per block
__global__ __launch_bounds__(256) void k_gemm_h(const float* __restrict__ x,
                                                const float* __restrict__ Wg,
                                                ushort_t* __restrict__ hb) {
    __shared__ float xs[16 * 128];
    int t = threadIdx.x;
    int n0 = blockIdx.x * 16;
#pragma unroll
    for (int r = 0; r < 8; ++r) {
        int idx = t + r * 256;
        xs[idx] = x[n0 * 128 + idx];
    }
    __syncthreads();
    float acc[16];
#pragma unroll
    for (int i = 0; i < 16; ++i) acc[i] = 0.f;
    for (int k = 0; k < 128; k += 4) {
        float w0 = Wg[(k + 0) * 256 + t];
        float w1 = Wg[(k + 1) * 256 + t];
        float w2 = Wg[(k + 2) * 256 + t];
        float w3 = Wg[(k + 3) * 256 + t];
#pragma unroll
        for (int i = 0; i < 16; ++i) {
            float4 xv = *(const float4*)&xs[i * 128 + k];
            acc[i] = fmaf(xv.x, w0, acc[i]);
            acc[i] = fmaf(xv.y, w1, acc[i]);
            acc[i] = fmaf(xv.z, w2, acc[i]);
            acc[i] = fmaf(xv.w, w3, acc[i]);
        }
    }
#pragma unroll
    for (int i = 0; i < 16; ++i) hb[(n0 + i) * 256 + t] = f2bf(acc[i]);
}

// a_s[n,h] / a_d[n,h] dot products from bf16 h; one thread per (node,head)
__global__ __launch_bounds__(256) void k_attn_coef(const ushort_t* __restrict__ hb,
                                                   const float* __restrict__ att_s,
                                                   const float* __restrict__ att_d,
                                                   float* __restrict__ a_s,
                                                   float* __restrict__ a_d) {
    int t = blockIdx.x * 256 + threadIdx.x;
    if (t >= N_NODES * HEADS) return;
    int n = t >> 3, hd = t & 7;
    const ushort_t* hp = hb + n * HC + hd * HID;
    const float* sp = att_s + hd * HID;
    const float* dp = att_d + hd * HID;
    float as = 0.f, ad = 0.f;
#pragma unroll
    for (int c = 0; c < HID; c += 8) {
        uint4 u = *(const uint4*)(hp + c);   // 8 bf16
        float h0 = bf_lo(u.x), h1 = bf_hi(u.x);
        float h2 = bf_lo(u.y), h3 = bf_hi(u.y);
        float h4 = bf_lo(u.z), h5 = bf_hi(u.z);
        float h6 = bf_lo(u.w), h7 = bf_hi(u.w);
        float4 s0 = *(const float4*)(sp + c);
        float4 s1 = *(const float4*)(sp + c + 4);
        float4 d0 = *(const float4*)(dp + c);
        float4 d1 = *(const float4*)(dp + c + 4);
        as += h0 * s0.x + h1 * s0.y + h2 * s0.z + h3 * s0.w
            + h4 * s1.x + h5 * s1.y + h6 * s1.z + h7 * s1.w;
        ad += h0 * d0.x + h1 * d0.y + h2 * d0.z + h3 * d0.w
            + h4 * d1.x + h5 * d1.y + h6 * d1.z + h7 * d1.w;
    }
    a_s[t] = as;
    a_d[t] = ad;
}

// ---------- CSR build ----------
__global__ __launch_bounds__(256) void k_hist(const int* __restrict__ ei,
                                              int* __restrict__ deg) {
    int e = blockIdx.x * 256 + threadIdx.x;
    if (e < N_EDGES) atomicAdd(&deg[ei[N_EDGES + e]], 1);
}

// phase 1: per-block exclusive scan of deg -> row (block-local), totals -> bsum
__global__ __launch_bounds__(256) void k_scan1(const int* __restrict__ deg,
                                               int* __restrict__ row,
                                               int* __restrict__ bsum) {
    __shared__ int s[256];
    int t = threadIdx.x;
    int i = blockIdx.x * 256 + t;
    int v = (i < N_NODES) ? deg[i] : 0;
    s[t] = v;
    __syncthreads();
    for (int off = 1; off < 256; off <<= 1) {
        int u = (t >= off) ? s[t - off] : 0;
        __syncthreads();
        s[t] += u;
        __syncthreads();
    }
    if (i < N_NODES) row[i] = s[t] - v;       // exclusive, block-local
    if (t == 255) bsum[blockIdx.x] = s[255];
}

// phase 2: single-block exclusive scan of the 196 block sums (in place)
__global__ __launch_bounds__(256) void k_scan2(int* __restrict__ bsum) {
    __shared__ int s[256];
    int t = threadIdx.x;
    int v = (t < SCAN_BLOCKS) ? bsum[t] : 0;
    s[t] = v;
    __syncthreads();
    for (int off = 1; off < 256; off <<= 1) {
        int u = (t >= off) ? s[t - off] : 0;
        __syncthreads();
        s[t] += u;
        __syncthreads();
    }
    if (t < SCAN_BLOCKS) bsum[t] = s[t] - v;  // exclusive
}

// phase 3: add block offsets; zero deg for reuse as scatter cursor
__global__ __launch_bounds__(256) void k_scan3(int* __restrict__ row,
                                               const int* __restrict__ bsum,
                                               int* __restrict__ deg) {
    int i = blockIdx.x * 256 + threadIdx.x;
    if (i < N_NODES) {
        row[i] += bsum[blockIdx.x];
        deg[i] = 0;
    }
    if (i == 0) row[N_NODES] = N_EDGES;       // sum of degrees is static
}

__global__ __launch_bounds__(256) void k_scatter(const int* __restrict__ ei,
                                                 const int* __restrict__ row,
                                                 int* __restrict__ fill,
                                                 int* __restrict__ csr) {
    int e = blockIdx.x * 256 + threadIdx.x;
    if (e >= N_EDGES) return;
    int d = ei[N_EDGES + e];
    int pos = row[d] + atomicAdd(&fill[d], 1);
    csr[pos] = ei[e];
}

// graph segment boundaries in sorted batch
__global__ __launch_bounds__(128) void k_bounds(const int* __restrict__ batch,
                                                int* __restrict__ gs) {
    int g = threadIdx.x;
    if (g > NG) return;
    int lo = 0, hi = N_NODES;
    while (lo < hi) {
        int mid = (lo + hi) >> 1;
        if (batch[mid] < g) lo = mid + 1; else hi = mid;
    }
    gs[g] = lo;
}

// ---------- fused GAT: per-dst softmax + bf16 gather-aggregate + bias + relu ----------
__global__ __launch_bounds__(256) void k_gat(const int* __restrict__ row,
                                             const int* __restrict__ csr,
                                             const float* __restrict__ a_s,
                                             const float* __restrict__ a_d,
                                             const ushort_t* __restrict__ hb,
                                             const float* __restrict__ bg,
                                             ushort_t* __restrict__ outb) {
    __shared__ int   s_src[4][MAXD];
    __shared__ float s_es[4][MAXD * 8];
    int g = threadIdx.x >> 6;
    int lane = threadIdx.x & 63;
    int n = blockIdx.x * 4 + g;            // N_NODES % 4 == 0
    int r0 = row[n], r1 = row[n + 1];
    int deg = r1 - r0;
    int E = deg + 1;                       // + implicit self loop
    bool cached = (E <= MAXD);
    if (cached) {
        for (int j = lane; j < deg; j += 64) s_src[g][j] = csr[r0 + j];
    }
    __syncthreads();

    int hd = lane & 7, jl = lane >> 3;     // 8 edge-lanes x 8 heads
    float ad = a_d[n * 8 + hd];
    float pmax = -1e30f;
    for (int j = jl; j < E; j += 8) {
        int sj = (j < deg) ? (cached ? s_src[g][j] : csr[r0 + j]) : n;
        float v = a_s[sj * 8 + hd] + ad;
        v = v > 0.f ? v : 0.2f * v;
        if (cached) s_es[g][j * 8 + hd] = v;
        pmax = fmaxf(pmax, v);
    }
#pragma unroll
    for (int mask = 8; mask <= 32; mask <<= 1)
        pmax = fmaxf(pmax, __shfl_xor(pmax, mask, 64));
    float psum = 0.f;
    for (int j = jl; j < E; j += 8) {
        float v;
        if (cached) v = s_es[g][j * 8 + hd];
        else {
            int sj = (j < deg) ? csr[r0 + j] : n;
            v = a_s[sj * 8 + hd] + ad;
            v = v > 0.f ? v : 0.2f * v;
        }
        psum += __expf(v - pmax);
    }
#pragma unroll
    for (int mask = 8; mask <= 32; mask <<= 1)
        psum += __shfl_xor(psum, mask, 64);
    float invden = 1.0f / psum;
    if (cached) {
        for (int j = jl; j < E; j += 8)
            s_es[g][j * 8 + hd] = __expf(s_es[g][j * 8 + hd] - pmax) * invden;
    }
    __syncthreads();

    // phase 2: lane owns channels [lane*4, lane*4+4), head hd2 = lane>>3
    int hd2 = lane >> 3;
    float m2 = __shfl(pmax, hd2, 64);
    float inv2 = __shfl(invden, hd2, 64);
    float ad2 = a_d[n * 8 + hd2];
    float4 acc = make_float4(0.f, 0.f, 0.f, 0.f);
    for (int j = 0; j < E; ++j) {
        int sj = (j < deg) ? (cached ? s_src[g][j] : csr[r0 + j]) : n;
        float alpha;
        if (cached) {
            alpha = s_es[g][j * 8 + hd2];
        } else {
            float v = a_s[sj * 8 + hd2] + ad2;
            v = v > 0.f ? v : 0.2f * v;
            alpha = __expf(v - m2) * inv2;
        }
        uint2 u = *(const uint2*)(hb + sj * HC + lane * 4);  // 4 bf16
        acc.x = fmaf(alpha, bf_lo(u.x), acc.x);
        acc.y = fmaf(alpha, bf_hi(u.x), acc.y);
        acc.z = fmaf(alpha, bf_lo(u.y), acc.z);
        acc.w = fmaf(alpha, bf_hi(u.y), acc.w);
    }
    float4 b = *(const float4*)(bg + lane * 4);
    acc.x = fmaxf(acc.x + b.x, 0.f);
    acc.y = fmaxf(acc.y + b.y, 0.f);
    acc.z = fmaxf(acc.z + b.z, 0.f);
    acc.w = fmaxf(acc.w + b.w, 0.f);
    uint2 o;
    o.x = (uint_t)f2bf(acc.x) | ((uint_t)f2bf(acc.y) << 16);
    o.y = (uint_t)f2bf(acc.z) | ((uint_t)f2bf(acc.w) << 16);
    *(uint2*)(outb + n * HC + lane * 4) = o;
}

// ---------- GIN gather (bf16 in, fp32 agg out) ----------
__global__ __launch_bounds__(256) void k_gin_gather(const int* __restrict__ row,
                                                    const int* __restrict__ csr,
                                                    const ushort_t* __restrict__ outb,
                                                    float* __restrict__ agg) {
    int g = threadIdx.x >> 6;
    int lane = threadIdx.x & 63;
    int n = blockIdx.x * 4 + g;
    int r0 = row[n], r1 = row[n + 1];
    uint2 u = *(const uint2*)(outb + n * HC + lane * 4);
    float4 acc = make_float4(bf_lo(u.x), bf_hi(u.x), bf_lo(u.y), bf_hi(u.y));
    for (int j = r0; j < r1; ++j) {
        int sj = csr[j];
        uint2 v = *(const uint2*)(outb + sj * HC + lane * 4);
        acc.x += bf_lo(v.x); acc.y += bf_hi(v.x);
        acc.z += bf_lo(v.y); acc.w += bf_hi(v.y);
    }
    *(float4*)(agg + n * HC + lane * 4) = acc;
}

// z = relu(relu(agg@W1+b1)@W2+b2), dense write, no atomics. 8 nodes/block.
__global__ __launch_bounds__(256) void k_mlp(const float* __restrict__ agg,
                                             const float* __restrict__ W1,
                                             const float* __restrict__ b1,
                                             const float* __restrict__ W2,
                                             const float* __restrict__ b2,
                                             float* __restrict__ z) {
    __shared__ float W1s[256 * 32];
    __shared__ float W2s[32 * 32];
    __shared__ float aggt[8 * 256];
    __shared__ float z1s[8 * 32];
    int t = threadIdx.x;
    int n0 = blockIdx.x * 8;
#pragma unroll
    for (int r = 0; r < 8; ++r)
        ((float4*)W1s)[t + r * 256] = ((const float4*)W1)[t + r * 256];
    ((float4*)W2s)[t] = ((const float4*)W2)[t];
#pragma unroll
    for (int r = 0; r < 2; ++r)
        ((float4*)aggt)[t + r * 256] = ((const float4*)(agg + n0 * HC))[t + r * 256];
    __syncthreads();
    int node = t >> 5, col = t & 31;
    float acc = b1[col];
    const float* ar = aggt + node * 256;
    for (int k = 0; k < 256; k += 4) {
        float4 av = *(const float4*)(ar + k);
        acc = fmaf(av.x, W1s[(k + 0) * 32 + col], acc);
        acc = fmaf(av.y, W1s[(k + 1) * 32 + col], acc);
        acc = fmaf(av.z, W1s[(k + 2) * 32 + col], acc);
        acc = fmaf(av.w, W1s[(k + 3) * 32 + col], acc);
    }
    z1s[node * 32 + col] = fmaxf(acc, 0.f);
    __syncthreads();
    float acc2 = b2[col];
    const float* zr = z1s + node * 32;
#pragma unroll
    for (int k = 0; k < 32; k += 4) {
        float4 zv = *(const float4*)(zr + k);
        acc2 = fmaf(zv.x, W2s[(k + 0) * 32 + col], acc2);
        acc2 = fmaf(zv.y, W2s[(k + 1) * 32 + col], acc2);
        acc2 = fmaf(zv.z, W2s[(k + 2) * 32 + col], acc2);
        acc2 = fmaf(zv.w, W2s[(k + 3) * 32 + col], acc2);
    }
    z[(n0 + node) * 32 + col] = fmaxf(acc2, 0.f);
}

// one block per graph: mean-pool its contiguous z rows, then @Wf + bf
__global__ __launch_bounds__(128) void k_pool_final(const float* __restrict__ z,
                                                    const int* __restrict__ gs,
                                                    const float* __restrict__ Wf,
                                                    const float* __restrict__ bf,
                                                    float* __restrict__ outp) {
    __shared__ float part[4][32];
    __shared__ float sums[32];
    int g = blockIdx.x;
    int t = threadIdx.x;
    int col = t & 31, q = t >> 5;
    int r0 = gs[g], r1 = gs[g + 1];
    float s = 0.f;
    for (int r = r0 + q; r < r1; r += 4) s += z[r * 32 + col];
    part[q][col] = s;
    __syncthreads();
    if (t < 32) sums[t] = part[0][t] + part[1][t] + part[2][t] + part[3][t];
    __syncthreads();
    float inv = 1.0f / fmaxf((float)(r1 - r0), 1.0f);
    float acc = 0.f;
#pragma unroll
    for (int k = 0; k < 32; ++k)
        acc = fmaf(sums[k], Wf[k * 128 + t], acc);
    outp[g * 128 + t] = acc * inv + bf[t];
}

extern "C" void kernel_launch(void* const* d_in, const int* in_sizes, int n_in,
                              void* d_out, int out_size, void* d_ws, size_t ws_size,
                              hipStream_t stream) {
    const float* x     = (const float*)d_in[0];
    const int*   ei    = (const int*)d_in[1];
    const int*   batch = (const int*)d_in[2];
    const float* Wg    = (const float*)d_in[3];
    const float* att_s = (const float*)d_in[4];
    const float* att_d = (const float*)d_in[5];
    const float* bg    = (const float*)d_in[6];
    const float* W1    = (const float*)d_in[7];
    const float* b1    = (const float*)d_in[8];
    const float* W2    = (const float*)d_in[9];
    const float* b2    = (const float*)d_in[10];
    const float* Wf    = (const float*)d_in[11];
    const float* bf    = (const float*)d_in[12];
    float* ws = (float*)d_ws;

    ushort_t* hb   = (ushort_t*)(ws + HB_OFF);
    ushort_t* outb = (ushort_t*)(ws + OUTB_OFF);
    float* a_s    = ws + AS_OFF;
    float* a_d    = ws + AD_OFF;
    int*   row    = (int*)(ws + ROW_OFF);
    int*   deg    = (int*)(ws + DEG_OFF);
    int*   csr    = (int*)(ws + CSR_OFF);
    int*   gs     = (int*)(ws + GS_OFF);
    int*   bsum   = (int*)(ws + BSUM_OFF);
    float* agg    = ws + AGG_OFF;           // overlays hb (hb dead after k_gat)
    float* z      = ws + Z_OFF;             // overlays outb (dead after GIN)

    // zero: deg (50000 ints)
    k_zero<<<(N_NODES / 4 + 255) / 256, 256, 0, stream>>>((float*)deg, N_NODES / 4);

    // CSR build (hierarchical scan) + graph bounds
    k_hist<<<(N_EDGES + 255) / 256, 256, 0, stream>>>(ei, deg);
    k_scan1<<<SCAN_BLOCKS, 256, 0, stream>>>(deg, row, bsum);
    k_scan2<<<1, 256, 0, stream>>>(bsum);
    k_scan3<<<SCAN_BLOCKS, 256, 0, stream>>>(row, bsum, deg);
    k_scatter<<<(N_EDGES + 255) / 256, 256, 0, stream>>>(ei, row, deg, csr);
    k_bounds<<<1, 128, 0, stream>>>(batch, gs);

    // GAT
    k_gemm_h<<<N_NODES / 16, 256, 0, stream>>>(x, Wg, hb);
    k_attn_coef<<<(N_NODES * HEADS + 255) / 256, 256, 0, stream>>>(hb, att_s, att_d, a_s, a_d);
    k_gat<<<N_NODES / 4, 256, 0, stream>>>(row, csr, a_s, a_d, hb, bg, outb);

    // GIN (agg overlays hb region; hb dead after k_gat)
    k_gin_gather<<<N_NODES / 4, 256, 0, stream>>>(row, csr, outb, agg);

    // MLP -> z (overlays outb), then per-graph pool + final linear
    k_mlp<<<N_NODES / 8, 256, 0, stream>>>(agg, W1, b1, W2, b2, z);
    k_pool_final<<<NG, 128, 0, stream>>>(z, gs, Wf, bf, (float*)d_out);
}

// Round 6
// 475.556 us; speedup vs baseline: 14.1472x; 1.1376x over previous
//
#include <hip/hip_runtime.h>

#define N_NODES 50000
#define N_EDGES 800000
#define HEADS   8
#define HID     32
#define HC      256
#define NG      64
#define MAXD    128   // per-node LDS edge cache; fallback path handles deg>=MAXD
#define SCAN_BLOCKS ((N_NODES + 255) / 256)   // 196

typedef unsigned short ushort_t;
typedef unsigned int   uint_t;

// ---- workspace layout (float offsets) ----
#define HB_OFF    0                // hb bf16 N*256 (25.6MB = 6.4M float slots)
#define Y_OFF     6400000          // y fp32 N*32 (= out@W1, pre-bias)
#define Z_OFF     8000000          // z fp32 N*32
#define AS_OFF    9600000          // a_s N*8 fp32
#define AD_OFF    10000000         // a_d N*8 fp32
#define ROW_OFF   10400000         // int row[N+1]
#define DEG_OFF   10450016         // int deg[N] (reused as fill cursor) [zero-init]
#define CSR_OFF   10500016         // int csr_src[N_EDGES]
#define GS_OFF    11300016         // int gstart[NG+1]
#define BSUM_OFF  11300088         // int bsum[SCAN_BLOCKS]
#define WS_END    11300284

__device__ __forceinline__ ushort_t f2bf(float f) {
    uint_t u = __float_as_uint(f);
    u = (u + 0x7FFFu + ((u >> 16) & 1u)) >> 16;   // RNE
    return (ushort_t)u;
}
__device__ __forceinline__ float bf_lo(uint_t u) { return __uint_as_float(u << 16); }
__device__ __forceinline__ float bf_hi(uint_t u) { return __uint_as_float(u & 0xFFFF0000u); }

__global__ __launch_bounds__(256) void k_zero(float* __restrict__ p, int n4) {
    int i = blockIdx.x * 256 + threadIdx.x;
    if (i < n4) ((float4*)p)[i] = make_float4(0.f, 0.f, 0.f, 0.f);
}

// hb = bf16(x @ W_gat), fused attention-coefficient epilogue.
// 16 nodes per block; thread t owns output column t.
__global__ __launch_bounds__(256) void k_gemm_h(const float* __restrict__ x,
                                                const float* __restrict__ Wg,
                                                const float* __restrict__ att_s,
                                                const float* __restrict__ att_d,
                                                ushort_t* __restrict__ hb,
                                                float* __restrict__ a_s,
                                                float* __restrict__ a_d) {
    __shared__ float xs[16 * 128];
    int t = threadIdx.x;
    int n0 = blockIdx.x * 16;
#pragma unroll
    for (int r = 0; r < 8; ++r) {
        int idx = t + r * 256;
        xs[idx] = x[n0 * 128 + idx];
    }
    __syncthreads();
    float acc[16];
#pragma unroll
    for (int i = 0; i < 16; ++i) acc[i] = 0.f;
    for (int k = 0; k < 128; k += 4) {
        float w0 = Wg[(k + 0) * 256 + t];
        float w1 = Wg[(k + 1) * 256 + t];
        float w2 = Wg[(k + 2) * 256 + t];
        float w3 = Wg[(k + 3) * 256 + t];
#pragma unroll
        for (int i = 0; i < 16; ++i) {
            float4 xv = *(const float4*)&xs[i * 128 + k];
            acc[i] = fmaf(xv.x, w0, acc[i]);
            acc[i] = fmaf(xv.y, w1, acc[i]);
            acc[i] = fmaf(xv.z, w2, acc[i]);
            acc[i] = fmaf(xv.w, w3, acc[i]);
        }
    }
#pragma unroll
    for (int i = 0; i < 16; ++i) hb[(n0 + i) * 256 + t] = f2bf(acc[i]);

    // attention epilogue: head = t>>5, channel-in-head = t&31; att flat idx = t
    float satt = att_s[t];
    float datt = att_d[t];
#pragma unroll
    for (int i = 0; i < 16; ++i) {
        float ps = acc[i] * satt;
        float pd = acc[i] * datt;
#pragma unroll
        for (int mask = 1; mask <= 16; mask <<= 1) {
            ps += __shfl_xor(ps, mask, 64);
            pd += __shfl_xor(pd, mask, 64);
        }
        if ((t & 31) == 0) {
            a_s[(n0 + i) * 8 + (t >> 5)] = ps;
            a_d[(n0 + i) * 8 + (t >> 5)] = pd;
        }
    }
}

// ---------- CSR build ----------
__global__ __launch_bounds__(256) void k_hist(const int* __restrict__ ei,
                                              int* __restrict__ deg) {
    int e = blockIdx.x * 256 + threadIdx.x;
    if (e < N_EDGES) atomicAdd(&deg[ei[N_EDGES + e]], 1);
}

// phase 1: per-block exclusive scan of deg -> row (block-local), totals -> bsum
__global__ __launch_bounds__(256) void k_scan1(const int* __restrict__ deg,
                                               int* __restrict__ row,
                                               int* __restrict__ bsum) {
    __shared__ int s[256];
    int t = threadIdx.x;
    int i = blockIdx.x * 256 + t;
    int v = (i < N_NODES) ? deg[i] : 0;
    s[t] = v;
    __syncthreads();
    for (int off = 1; off < 256; off <<= 1) {
        int u = (t >= off) ? s[t - off] : 0;
        __syncthreads();
        s[t] += u;
        __syncthreads();
    }
    if (i < N_NODES) row[i] = s[t] - v;       // exclusive, block-local
    if (t == 255) bsum[blockIdx.x] = s[255];
}

// phase 2: scan the 196 block sums; also compute graph bounds (independent work)
__global__ __launch_bounds__(256) void k_scan2(int* __restrict__ bsum,
                                               const int* __restrict__ batch,
                                               int* __restrict__ gs) {
    __shared__ int s[256];
    int t = threadIdx.x;
    int v = (t < SCAN_BLOCKS) ? bsum[t] : 0;
    s[t] = v;
    __syncthreads();
    for (int off = 1; off < 256; off <<= 1) {
        int u = (t >= off) ? s[t - off] : 0;
        __syncthreads();
        s[t] += u;
        __syncthreads();
    }
    if (t < SCAN_BLOCKS) bsum[t] = s[t] - v;  // exclusive
    // graph segment boundaries in sorted batch
    if (t <= NG) {
        int lo = 0, hi = N_NODES;
        while (lo < hi) {
            int mid = (lo + hi) >> 1;
            if (batch[mid] < t) lo = mid + 1; else hi = mid;
        }
        gs[t] = lo;
    }
}

// phase 3: add block offsets; zero deg for reuse as scatter cursor
__global__ __launch_bounds__(256) void k_scan3(int* __restrict__ row,
                                               const int* __restrict__ bsum,
                                               int* __restrict__ deg) {
    int i = blockIdx.x * 256 + threadIdx.x;
    if (i < N_NODES) {
        row[i] += bsum[blockIdx.x];
        deg[i] = 0;
    }
    if (i == 0) row[N_NODES] = N_EDGES;       // sum of degrees is static
}

__global__ __launch_bounds__(256) void k_scatter(const int* __restrict__ ei,
                                                 const int* __restrict__ row,
                                                 int* __restrict__ fill,
                                                 int* __restrict__ csr) {
    int e = blockIdx.x * 256 + threadIdx.x;
    if (e >= N_EDGES) return;
    int d = ei[N_EDGES + e];
    int pos = row[d] + atomicAdd(&fill[d], 1);
    csr[pos] = ei[e];
}

// ---------- fused GAT: softmax + bf16 gather-aggregate + bias + relu + @W1 ----------
// out rows are NEVER materialized: the epilogue projects relu(out) @ W1 -> y (N x 32).
__global__ __launch_bounds__(256) void k_gat(const int* __restrict__ row,
                                             const int* __restrict__ csr,
                                             const float* __restrict__ a_s,
                                             const float* __restrict__ a_d,
                                             const ushort_t* __restrict__ hb,
                                             const float* __restrict__ bg,
                                             const float* __restrict__ W1,
                                             float* __restrict__ y) {
    __shared__ int   s_src[4][MAXD];
    __shared__ float s_es[4][MAXD * 8];
    int g = threadIdx.x >> 6;
    int lane = threadIdx.x & 63;
    int n = blockIdx.x * 4 + g;            // N_NODES % 4 == 0
    int r0 = row[n], r1 = row[n + 1];
    int deg = r1 - r0;
    int E = deg + 1;                       // + implicit self loop
    bool cached = (E <= MAXD);
    if (cached) {
        for (int j = lane; j < deg; j += 64) s_src[g][j] = csr[r0 + j];
    }
    __syncthreads();

    int hd = lane & 7, jl = lane >> 3;     // 8 edge-lanes x 8 heads
    float ad = a_d[n * 8 + hd];
    float pmax = -1e30f;
    for (int j = jl; j < E; j += 8) {
        int sj = (j < deg) ? (cached ? s_src[g][j] : csr[r0 + j]) : n;
        float v = a_s[sj * 8 + hd] + ad;
        v = v > 0.f ? v : 0.2f * v;
        if (cached) s_es[g][j * 8 + hd] = v;
        pmax = fmaxf(pmax, v);
    }
#pragma unroll
    for (int mask = 8; mask <= 32; mask <<= 1)
        pmax = fmaxf(pmax, __shfl_xor(pmax, mask, 64));
    float psum = 0.f;
    for (int j = jl; j < E; j += 8) {
        float v;
        if (cached) v = s_es[g][j * 8 + hd];
        else {
            int sj = (j < deg) ? csr[r0 + j] : n;
            v = a_s[sj * 8 + hd] + ad;
            v = v > 0.f ? v : 0.2f * v;
        }
        psum += __expf(v - pmax);
    }
#pragma unroll
    for (int mask = 8; mask <= 32; mask <<= 1)
        psum += __shfl_xor(psum, mask, 64);
    float invden = 1.0f / psum;
    if (cached) {
        for (int j = jl; j < E; j += 8)
            s_es[g][j * 8 + hd] = __expf(s_es[g][j * 8 + hd] - pmax) * invden;
    }
    __syncthreads();

    // phase 2: lane owns channels [lane*4, lane*4+4), head hd2 = lane>>3
    int hd2 = lane >> 3;
    float m2 = __shfl(pmax, hd2, 64);
    float inv2 = __shfl(invden, hd2, 64);
    float ad2 = a_d[n * 8 + hd2];
    float4 acc = make_float4(0.f, 0.f, 0.f, 0.f);
    for (int j = 0; j < E; ++j) {
        int sj = (j < deg) ? (cached ? s_src[g][j] : csr[r0 + j]) : n;
        float alpha;
        if (cached) {
            alpha = s_es[g][j * 8 + hd2];
        } else {
            float v = a_s[sj * 8 + hd2] + ad2;
            v = v > 0.f ? v : 0.2f * v;
            alpha = __expf(v - m2) * inv2;
        }
        uint2 u = *(const uint2*)(hb + sj * HC + lane * 4);  // 4 bf16
        acc.x = fmaf(alpha, bf_lo(u.x), acc.x);
        acc.y = fmaf(alpha, bf_hi(u.x), acc.y);
        acc.z = fmaf(alpha, bf_lo(u.y), acc.z);
        acc.w = fmaf(alpha, bf_hi(u.y), acc.w);
    }
    float4 b = *(const float4*)(bg + lane * 4);
    acc.x = fmaxf(acc.x + b.x, 0.f);
    acc.y = fmaxf(acc.y + b.y, 0.f);
    acc.z = fmaxf(acc.z + b.z, 0.f);
    acc.w = fmaxf(acc.w + b.w, 0.f);

    // epilogue: y[n] = out_row @ W1 (256 -> 32). Reuse s_es[g] as the fp32 row.
    float* srow = &s_es[g][0];
    *(float4*)(srow + lane * 4) = acc;
    __syncthreads();
    int col = lane & 31;
    int c0 = (lane >> 5) * 128;            // two lanes per col, half-row each
    float yv = 0.f;
    for (int c = c0; c < c0 + 128; c += 4) {
        float4 r = *(const float4*)(srow + c);
        yv = fmaf(r.x, W1[(c + 0) * 32 + col], yv);
        yv = fmaf(r.y, W1[(c + 1) * 32 + col], yv);
        yv = fmaf(r.z, W1[(c + 2) * 32 + col], yv);
        yv = fmaf(r.w, W1[(c + 3) * 32 + col], yv);
    }
    yv += __shfl_xor(yv, 32, 64);
    if (lane < 32) y[n * 32 + col] = yv;
}

// ---------- GIN gather on y (128 B rows) + MLP layer 2, dense z write ----------
// z[n] = relu( relu(y[n] + sum_j y[src_j] + b1) @ W2 + b2 ).  8 nodes/block.
__global__ __launch_bounds__(256) void k_gin_mlp(const int* __restrict__ row,
                                                 const int* __restrict__ csr,
                                                 const float* __restrict__ y,
                                                 const float* __restrict__ b1,
                                                 const float* __restrict__ W2,
                                                 const float* __restrict__ b2,
                                                 float* __restrict__ z) {
    __shared__ float W2s[32 * 32];
    __shared__ float z1s[8][32];
    int t = threadIdx.x;
    ((float4*)W2s)[t] = ((const float4*)W2)[t];
    int node = t >> 5, col = t & 31;
    int n = blockIdx.x * 8 + node;
    int r0 = row[n], r1 = row[n + 1];
    float acc = y[n * 32 + col] + b1[col];
    int j = r0;
    for (; j + 1 < r1; j += 2) {
        int s0 = csr[j], s1 = csr[j + 1];
        acc += y[s0 * 32 + col] + y[s1 * 32 + col];
    }
    if (j < r1) acc += y[csr[j] * 32 + col];
    z1s[node][col] = fmaxf(acc, 0.f);
    __syncthreads();
    float acc2 = b2[col];
    const float* zr = z1s[node];
#pragma unroll
    for (int k = 0; k < 32; k += 4) {
        float4 zv = *(const float4*)(zr + k);
        acc2 = fmaf(zv.x, W2s[(k + 0) * 32 + col], acc2);
        acc2 = fmaf(zv.y, W2s[(k + 1) * 32 + col], acc2);
        acc2 = fmaf(zv.z, W2s[(k + 2) * 32 + col], acc2);
        acc2 = fmaf(zv.w, W2s[(k + 3) * 32 + col], acc2);
    }
    z[n * 32 + col] = fmaxf(acc2, 0.f);
}

// one block per graph: mean-pool its contiguous z rows, then @Wf + bf
__global__ __launch_bounds__(128) void k_pool_final(const float* __restrict__ z,
                                                    const int* __restrict__ gs,
                                                    const float* __restrict__ Wf,
                                                    const float* __restrict__ bf,
                                                    float* __restrict__ outp) {
    __shared__ float part[4][32];
    __shared__ float sums[32];
    int g = blockIdx.x;
    int t = threadIdx.x;
    int col = t & 31, q = t >> 5;
    int r0 = gs[g], r1 = gs[g + 1];
    float s = 0.f;
    for (int r = r0 + q; r < r1; r += 4) s += z[r * 32 + col];
    part[q][col] = s;
    __syncthreads();
    if (t < 32) sums[t] = part[0][t] + part[1][t] + part[2][t] + part[3][t];
    __syncthreads();
    float inv = 1.0f / fmaxf((float)(r1 - r0), 1.0f);
    float acc = 0.f;
#pragma unroll
    for (int k = 0; k < 32; ++k)
        acc = fmaf(sums[k], Wf[k * 128 + t], acc);
    outp[g * 128 + t] = acc * inv + bf[t];
}

extern "C" void kernel_launch(void* const* d_in, const int* in_sizes, int n_in,
                              void* d_out, int out_size, void* d_ws, size_t ws_size,
                              hipStream_t stream) {
    const float* x     = (const float*)d_in[0];
    const int*   ei    = (const int*)d_in[1];
    const int*   batch = (const int*)d_in[2];
    const float* Wg    = (const float*)d_in[3];
    const float* att_s = (const float*)d_in[4];
    const float* att_d = (const float*)d_in[5];
    const float* bg    = (const float*)d_in[6];
    const float* W1    = (const float*)d_in[7];
    const float* b1    = (const float*)d_in[8];
    const float* W2    = (const float*)d_in[9];
    const float* b2    = (const float*)d_in[10];
    const float* Wf    = (const float*)d_in[11];
    const float* bf    = (const float*)d_in[12];
    float* ws = (float*)d_ws;

    ushort_t* hb  = (ushort_t*)(ws + HB_OFF);
    float* y      = ws + Y_OFF;
    float* z      = ws + Z_OFF;
    float* a_s    = ws + AS_OFF;
    float* a_d    = ws + AD_OFF;
    int*   row    = (int*)(ws + ROW_OFF);
    int*   deg    = (int*)(ws + DEG_OFF);
    int*   csr    = (int*)(ws + CSR_OFF);
    int*   gs     = (int*)(ws + GS_OFF);
    int*   bsum   = (int*)(ws + BSUM_OFF);

    // zero: deg (50000 ints)
    k_zero<<<(N_NODES / 4 + 255) / 256, 256, 0, stream>>>((float*)deg, N_NODES / 4);

    // CSR build (hierarchical scan; bounds merged into scan2)
    k_hist<<<(N_EDGES + 255) / 256, 256, 0, stream>>>(ei, deg);
    k_scan1<<<SCAN_BLOCKS, 256, 0, stream>>>(deg, row, bsum);
    k_scan2<<<1, 256, 0, stream>>>(bsum, batch, gs);
    k_scan3<<<SCAN_BLOCKS, 256, 0, stream>>>(row, bsum, deg);
    k_scatter<<<(N_EDGES + 255) / 256, 256, 0, stream>>>(ei, row, deg, csr);

    // GAT projection + attention coefficients (fused)
    k_gemm_h<<<N_NODES / 16, 256, 0, stream>>>(x, Wg, att_s, att_d, hb, a_s, a_d);
    // fused GAT: softmax + gather + bias/relu + @W1 -> y  (out never materialized)
    k_gat<<<N_NODES / 4, 256, 0, stream>>>(row, csr, a_s, a_d, hb, bg, W1, y);

    // GIN on projected y + MLP layer 2 -> z
    k_gin_mlp<<<N_NODES / 8, 256, 0, stream>>>(row, csr, y, b1, W2, b2, z);

    // per-graph mean pool + final linear
    k_pool_final<<<NG, 128, 0, stream>>>(z, gs, Wf, bf, (float*)d_out);
}

// Round 7
// 461.743 us; speedup vs baseline: 14.5704x; 1.0299x over previous
//
#include <hip/hip_runtime.h>

#define N_NODES 50000
#define N_EDGES 800000
#define HEADS   8
#define HID     32
#define HC      256
#define NG      64
#define MAXD    128   // per-node LDS edge cache; fallback path handles deg>=MAXD
#define SCAN_BLOCKS ((N_NODES + 255) / 256)   // 196

typedef unsigned short ushort_t;
typedef unsigned int   uint_t;

// ---- workspace layout (float offsets) ----
#define HB_OFF    0                // hb bf16 N*256 (25.6MB = 6.4M float slots)
#define Y_OFF     6400000          // y fp32 N*32 (= out@W1, pre-bias)
#define Z_OFF     8000000          // z fp32 N*32
#define AS_OFF    9600000          // a_s N*8 fp32
#define AD_OFF    10000000         // a_d N*8 fp32
#define ROW_OFF   10400000         // int row[N+1]
#define DEG_OFF   10450016         // int deg[N] (reused as fill cursor) [zero-init]
#define CSR_OFF   10500016         // int csr_src[N_EDGES]
#define GS_OFF    11300016         // int gstart[NG+1]
#define BSUM_OFF  11300088         // int bsum[SCAN_BLOCKS]
#define WS_END    11300284

__device__ __forceinline__ ushort_t f2bf(float f) {
    uint_t u = __float_as_uint(f);
    u = (u + 0x7FFFu + ((u >> 16) & 1u)) >> 16;   // RNE
    return (ushort_t)u;
}
__device__ __forceinline__ float bf_lo(uint_t u) { return __uint_as_float(u << 16); }
__device__ __forceinline__ float bf_hi(uint_t u) { return __uint_as_float(u & 0xFFFF0000u); }

__global__ __launch_bounds__(256) void k_zero(float* __restrict__ p, int n4) {
    int i = blockIdx.x * 256 + threadIdx.x;
    if (i < n4) ((float4*)p)[i] = make_float4(0.f, 0.f, 0.f, 0.f);
}

// hb = bf16(x @ W_gat), fused attention-coefficient epilogue.
// 16 nodes per block; thread t owns output column t.
__global__ __launch_bounds__(256) void k_gemm_h(const float* __restrict__ x,
                                                const float* __restrict__ Wg,
                                                const float* __restrict__ att_s,
                                                const float* __restrict__ att_d,
                                                ushort_t* __restrict__ hb,
                                                float* __restrict__ a_s,
                                                float* __restrict__ a_d) {
    __shared__ float xs[16 * 128];
    int t = threadIdx.x;
    int n0 = blockIdx.x * 16;
#pragma unroll
    for (int r = 0; r < 8; ++r) {
        int idx = t + r * 256;
        xs[idx] = x[n0 * 128 + idx];
    }
    __syncthreads();
    float acc[16];
#pragma unroll
    for (int i = 0; i < 16; ++i) acc[i] = 0.f;
    for (int k = 0; k < 128; k += 4) {
        float w0 = Wg[(k + 0) * 256 + t];
        float w1 = Wg[(k + 1) * 256 + t];
        float w2 = Wg[(k + 2) * 256 + t];
        float w3 = Wg[(k + 3) * 256 + t];
#pragma unroll
        for (int i = 0; i < 16; ++i) {
            float4 xv = *(const float4*)&xs[i * 128 + k];
            acc[i] = fmaf(xv.x, w0, acc[i]);
            acc[i] = fmaf(xv.y, w1, acc[i]);
            acc[i] = fmaf(xv.z, w2, acc[i]);
            acc[i] = fmaf(xv.w, w3, acc[i]);
        }
    }
#pragma unroll
    for (int i = 0; i < 16; ++i) hb[(n0 + i) * 256 + t] = f2bf(acc[i]);

    // attention epilogue: head = t>>5, channel-in-head = t&31; att flat idx = t
    float satt = att_s[t];
    float datt = att_d[t];
#pragma unroll
    for (int i = 0; i < 16; ++i) {
        float ps = acc[i] * satt;
        float pd = acc[i] * datt;
#pragma unroll
        for (int mask = 1; mask <= 16; mask <<= 1) {
            ps += __shfl_xor(ps, mask, 64);
            pd += __shfl_xor(pd, mask, 64);
        }
        if ((t & 31) == 0) {
            a_s[(n0 + i) * 8 + (t >> 5)] = ps;
            a_d[(n0 + i) * 8 + (t >> 5)] = pd;
        }
    }
}

// ---------- CSR build ----------
__global__ __launch_bounds__(256) void k_hist(const int* __restrict__ ei,
                                              int* __restrict__ deg) {
    int e = blockIdx.x * 256 + threadIdx.x;
    if (e < N_EDGES) atomicAdd(&deg[ei[N_EDGES + e]], 1);
}

// phase 1: per-block exclusive scan of deg -> row (block-local), totals -> bsum
__global__ __launch_bounds__(256) void k_scan1(const int* __restrict__ deg,
                                               int* __restrict__ row,
                                               int* __restrict__ bsum) {
    __shared__ int s[256];
    int t = threadIdx.x;
    int i = blockIdx.x * 256 + t;
    int v = (i < N_NODES) ? deg[i] : 0;
    s[t] = v;
    __syncthreads();
    for (int off = 1; off < 256; off <<= 1) {
        int u = (t >= off) ? s[t - off] : 0;
        __syncthreads();
        s[t] += u;
        __syncthreads();
    }
    if (i < N_NODES) row[i] = s[t] - v;       // exclusive, block-local
    if (t == 255) bsum[blockIdx.x] = s[255];
}

// phase 2: scan the 196 block sums; also compute graph bounds (independent work)
__global__ __launch_bounds__(256) void k_scan2(int* __restrict__ bsum,
                                               const int* __restrict__ batch,
                                               int* __restrict__ gs) {
    __shared__ int s[256];
    int t = threadIdx.x;
    int v = (t < SCAN_BLOCKS) ? bsum[t] : 0;
    s[t] = v;
    __syncthreads();
    for (int off = 1; off < 256; off <<= 1) {
        int u = (t >= off) ? s[t - off] : 0;
        __syncthreads();
        s[t] += u;
        __syncthreads();
    }
    if (t < SCAN_BLOCKS) bsum[t] = s[t] - v;  // exclusive
    // graph segment boundaries in sorted batch
    if (t <= NG) {
        int lo = 0, hi = N_NODES;
        while (lo < hi) {
            int mid = (lo + hi) >> 1;
            if (batch[mid] < t) lo = mid + 1; else hi = mid;
        }
        gs[t] = lo;
    }
}

// phase 3: add block offsets; zero deg for reuse as scatter cursor
__global__ __launch_bounds__(256) void k_scan3(int* __restrict__ row,
                                               const int* __restrict__ bsum,
                                               int* __restrict__ deg) {
    int i = blockIdx.x * 256 + threadIdx.x;
    if (i < N_NODES) {
        row[i] += bsum[blockIdx.x];
        deg[i] = 0;
    }
    if (i == 0) row[N_NODES] = N_EDGES;       // sum of degrees is static
}

__global__ __launch_bounds__(256) void k_scatter(const int* __restrict__ ei,
                                                 const int* __restrict__ row,
                                                 int* __restrict__ fill,
                                                 int* __restrict__ csr) {
    int e = blockIdx.x * 256 + threadIdx.x;
    if (e >= N_EDGES) return;
    int d = ei[N_EDGES + e];
    int pos = row[d] + atomicAdd(&fill[d], 1);
    csr[pos] = ei[e];
}

// ---------- fused GAT: softmax + bf16 gather-aggregate + bias + relu + @W1 ----------
// One wave per node; ALL LDS state is per-wave-private (s_src[g], s_es[g]) so NO
// __syncthreads() anywhere: intra-wave ds ordering is handled by lgkmcnt waits,
// and block barriers would only serialize waves with divergent degrees.
__global__ __launch_bounds__(256) void k_gat(const int* __restrict__ row,
                                             const int* __restrict__ csr,
                                             const float* __restrict__ a_s,
                                             const float* __restrict__ a_d,
                                             const ushort_t* __restrict__ hb,
                                             const float* __restrict__ bg,
                                             const float* __restrict__ W1,
                                             float* __restrict__ y) {
    __shared__ int   s_src[4][MAXD];
    __shared__ float s_es[4][MAXD * 8];
    int g = threadIdx.x >> 6;
    int lane = threadIdx.x & 63;
    int n = blockIdx.x * 4 + g;            // N_NODES % 4 == 0
    int r0 = row[n], r1 = row[n + 1];
    int deg = r1 - r0;
    int E = deg + 1;                       // + implicit self loop
    bool cached = (E <= MAXD);
    if (cached) {
        for (int j = lane; j < deg; j += 64) s_src[g][j] = csr[r0 + j];
    }

    int hd = lane & 7, jl = lane >> 3;     // 8 edge-lanes x 8 heads
    float ad = a_d[n * 8 + hd];
    float pmax = -1e30f;
    for (int j = jl; j < E; j += 8) {
        int sj = (j < deg) ? (cached ? s_src[g][j] : csr[r0 + j]) : n;
        float v = a_s[sj * 8 + hd] + ad;
        v = v > 0.f ? v : 0.2f * v;
        if (cached) s_es[g][j * 8 + hd] = v;
        pmax = fmaxf(pmax, v);
    }
#pragma unroll
    for (int mask = 8; mask <= 32; mask <<= 1)
        pmax = fmaxf(pmax, __shfl_xor(pmax, mask, 64));
    float psum = 0.f;
    for (int j = jl; j < E; j += 8) {
        float v;
        if (cached) v = s_es[g][j * 8 + hd];
        else {
            int sj = (j < deg) ? csr[r0 + j] : n;
            v = a_s[sj * 8 + hd] + ad;
            v = v > 0.f ? v : 0.2f * v;
        }
        psum += __expf(v - pmax);
    }
#pragma unroll
    for (int mask = 8; mask <= 32; mask <<= 1)
        psum += __shfl_xor(psum, mask, 64);
    float invden = 1.0f / psum;
    if (cached) {
        for (int j = jl; j < E; j += 8)
            s_es[g][j * 8 + hd] = __expf(s_es[g][j * 8 + hd] - pmax) * invden;
    }

    // phase 2: lane owns channels [lane*4, lane*4+4), head hd2 = lane>>3
    int hd2 = lane >> 3;
    float m2 = __shfl(pmax, hd2, 64);
    float inv2 = __shfl(invden, hd2, 64);
    float ad2 = a_d[n * 8 + hd2];
    float4 acc = make_float4(0.f, 0.f, 0.f, 0.f);
    for (int j = 0; j < E; ++j) {
        int sj = (j < deg) ? (cached ? s_src[g][j] : csr[r0 + j]) : n;
        float alpha;
        if (cached) {
            alpha = s_es[g][j * 8 + hd2];
        } else {
            float v = a_s[sj * 8 + hd2] + ad2;
            v = v > 0.f ? v : 0.2f * v;
            alpha = __expf(v - m2) * inv2;
        }
        uint2 u = *(const uint2*)(hb + sj * HC + lane * 4);  // 4 bf16
        acc.x = fmaf(alpha, bf_lo(u.x), acc.x);
        acc.y = fmaf(alpha, bf_hi(u.x), acc.y);
        acc.z = fmaf(alpha, bf_lo(u.y), acc.z);
        acc.w = fmaf(alpha, bf_hi(u.y), acc.w);
    }
    float4 b = *(const float4*)(bg + lane * 4);
    acc.x = fmaxf(acc.x + b.x, 0.f);
    acc.y = fmaxf(acc.y + b.y, 0.f);
    acc.z = fmaxf(acc.z + b.z, 0.f);
    acc.w = fmaxf(acc.w + b.w, 0.f);

    // epilogue: y[n] = out_row @ W1 (256 -> 32). Reuse s_es[g] (wave-private).
    float* srow = &s_es[g][0];
    *(float4*)(srow + lane * 4) = acc;
    int col = lane & 31;
    int c0 = (lane >> 5) * 128;            // two lanes per col, half-row each
    float yv = 0.f;
    for (int c = c0; c < c0 + 128; c += 4) {
        float4 r = *(const float4*)(srow + c);
        yv = fmaf(r.x, W1[(c + 0) * 32 + col], yv);
        yv = fmaf(r.y, W1[(c + 1) * 32 + col], yv);
        yv = fmaf(r.z, W1[(c + 2) * 32 + col], yv);
        yv = fmaf(r.w, W1[(c + 3) * 32 + col], yv);
    }
    yv += __shfl_xor(yv, 32, 64);
    if (lane < 32) y[n * 32 + col] = yv;
}

// ---------- GIN gather on y (128 B rows) + MLP layer 2, dense z write ----------
// z[n] = relu( relu(y[n] + sum_j y[src_j] + b1) @ W2 + b2 ).  8 nodes/block.
__global__ __launch_bounds__(256) void k_gin_mlp(const int* __restrict__ row,
                                                 const int* __restrict__ csr,
                                                 const float* __restrict__ y,
                                                 const float* __restrict__ b1,
                                                 const float* __restrict__ W2,
                                                 const float* __restrict__ b2,
                                                 float* __restrict__ z) {
    __shared__ float W2s[32 * 32];
    __shared__ float z1s[8][32];
    int t = threadIdx.x;
    ((float4*)W2s)[t] = ((const float4*)W2)[t];
    int node = t >> 5, col = t & 31;
    int n = blockIdx.x * 8 + node;
    int r0 = row[n], r1 = row[n + 1];
    float acc = y[n * 32 + col] + b1[col];
    int j = r0;
    for (; j + 1 < r1; j += 2) {
        int s0 = csr[j], s1 = csr[j + 1];
        acc += y[s0 * 32 + col] + y[s1 * 32 + col];
    }
    if (j < r1) acc += y[csr[j] * 32 + col];
    z1s[node][col] = fmaxf(acc, 0.f);
    __syncthreads();   // needed: W2s staging crosses waves
    float acc2 = b2[col];
    const float* zr = z1s[node];
#pragma unroll
    for (int k = 0; k < 32; k += 4) {
        float4 zv = *(const float4*)(zr + k);
        acc2 = fmaf(zv.x, W2s[(k + 0) * 32 + col], acc2);
        acc2 = fmaf(zv.y, W2s[(k + 1) * 32 + col], acc2);
        acc2 = fmaf(zv.z, W2s[(k + 2) * 32 + col], acc2);
        acc2 = fmaf(zv.w, W2s[(k + 3) * 32 + col], acc2);
    }
    z[n * 32 + col] = fmaxf(acc2, 0.f);
}

// one block per graph: mean-pool its contiguous z rows, then @Wf + bf
__global__ __launch_bounds__(128) void k_pool_final(const float* __restrict__ z,
                                                    const int* __restrict__ gs,
                                                    const float* __restrict__ Wf,
                                                    const float* __restrict__ bf,
                                                    float* __restrict__ outp) {
    __shared__ float part[4][32];
    __shared__ float sums[32];
    int g = blockIdx.x;
    int t = threadIdx.x;
    int col = t & 31, q = t >> 5;
    int r0 = gs[g], r1 = gs[g + 1];
    float s = 0.f;
    for (int r = r0 + q; r < r1; r += 4) s += z[r * 32 + col];
    part[q][col] = s;
    __syncthreads();
    if (t < 32) sums[t] = part[0][t] + part[1][t] + part[2][t] + part[3][t];
    __syncthreads();
    float inv = 1.0f / fmaxf((float)(r1 - r0), 1.0f);
    float acc = 0.f;
#pragma unroll
    for (int k = 0; k < 32; ++k)
        acc = fmaf(sums[k], Wf[k * 128 + t], acc);
    outp[g * 128 + t] = acc * inv + bf[t];
}

extern "C" void kernel_launch(void* const* d_in, const int* in_sizes, int n_in,
                              void* d_out, int out_size, void* d_ws, size_t ws_size,
                              hipStream_t stream) {
    const float* x     = (const float*)d_in[0];
    const int*   ei    = (const int*)d_in[1];
    const int*   batch = (const int*)d_in[2];
    const float* Wg    = (const float*)d_in[3];
    const float* att_s = (const float*)d_in[4];
    const float* att_d = (const float*)d_in[5];
    const float* bg    = (const float*)d_in[6];
    const float* W1    = (const float*)d_in[7];
    const float* b1    = (const float*)d_in[8];
    const float* W2    = (const float*)d_in[9];
    const float* b2    = (const float*)d_in[10];
    const float* Wf    = (const float*)d_in[11];
    const float* bf    = (const float*)d_in[12];
    float* ws = (float*)d_ws;

    ushort_t* hb  = (ushort_t*)(ws + HB_OFF);
    float* y      = ws + Y_OFF;
    float* z      = ws + Z_OFF;
    float* a_s    = ws + AS_OFF;
    float* a_d    = ws + AD_OFF;
    int*   row    = (int*)(ws + ROW_OFF);
    int*   deg    = (int*)(ws + DEG_OFF);
    int*   csr    = (int*)(ws + CSR_OFF);
    int*   gs     = (int*)(ws + GS_OFF);
    int*   bsum   = (int*)(ws + BSUM_OFF);

    // zero: deg (50000 ints)
    k_zero<<<(N_NODES / 4 + 255) / 256, 256, 0, stream>>>((float*)deg, N_NODES / 4);

    // CSR build (hierarchical scan; bounds merged into scan2)
    k_hist<<<(N_EDGES + 255) / 256, 256, 0, stream>>>(ei, deg);
    k_scan1<<<SCAN_BLOCKS, 256, 0, stream>>>(deg, row, bsum);
    k_scan2<<<1, 256, 0, stream>>>(bsum, batch, gs);
    k_scan3<<<SCAN_BLOCKS, 256, 0, stream>>>(row, bsum, deg);
    k_scatter<<<(N_EDGES + 255) / 256, 256, 0, stream>>>(ei, row, deg, csr);

    // GAT projection + attention coefficients (fused)
    k_gemm_h<<<N_NODES / 16, 256, 0, stream>>>(x, Wg, att_s, att_d, hb, a_s, a_d);
    // fused GAT: softmax + gather + bias/relu + @W1 -> y  (out never materialized)
    k_gat<<<N_NODES / 4, 256, 0, stream>>>(row, csr, a_s, a_d, hb, bg, W1, y);

    // GIN on projected y + MLP layer 2 -> z
    k_gin_mlp<<<N_NODES / 8, 256, 0, stream>>>(row, csr, y, b1, W2, b2, z);

    // per-graph mean pool + final linear
    k_pool_final<<<NG, 128, 0, stream>>>(z, gs, Wf, bf, (float*)d_out);
}

// Round 8
// 432.263 us; speedup vs baseline: 15.5641x; 1.0682x over previous
//
#include <hip/hip_runtime.h>

#define N_NODES 50000
#define N_EDGES 800000
#define HEADS   8
#define HID     32
#define HC      256
#define NG      64
#define MAXD    64    // per-node LDS edge cache (incl self-loop); fallback if E>MAXD
#define SCAN_BLOCKS ((N_NODES + 255) / 256)   // 196

typedef unsigned short ushort_t;
typedef unsigned int   uint_t;

// ---- workspace layout (float offsets) ----
#define HB_OFF    0                // hb bf16 N*256 (25.6MB = 6.4M float slots)
#define Y_OFF     6400000          // y fp32 N*32 (= out@W1, pre-bias)
#define Z_OFF     8000000          // z fp32 N*32
#define AS_OFF    9600000          // a_s N*8 fp32
#define AD_OFF    10000000         // a_d N*8 fp32
#define ROW_OFF   10400000         // int row[N+1]
#define DEG_OFF   10450016         // int deg[N] (reused as fill cursor) [zero-init]
#define CSR_OFF   10500016         // int csr_src[N_EDGES]
#define GS_OFF    11300016         // int gstart[NG+1]
#define BSUM_OFF  11300088         // int bsum[SCAN_BLOCKS]
#define WS_END    11300284

__device__ __forceinline__ ushort_t f2bf(float f) {
    uint_t u = __float_as_uint(f);
    u = (u + 0x7FFFu + ((u >> 16) & 1u)) >> 16;   // RNE
    return (ushort_t)u;
}
__device__ __forceinline__ float bf_lo(uint_t u) { return __uint_as_float(u << 16); }
__device__ __forceinline__ float bf_hi(uint_t u) { return __uint_as_float(u & 0xFFFF0000u); }

__global__ __launch_bounds__(256) void k_zero(float* __restrict__ p, int n4) {
    int i = blockIdx.x * 256 + threadIdx.x;
    if (i < n4) ((float4*)p)[i] = make_float4(0.f, 0.f, 0.f, 0.f);
}

// hb = bf16(x @ W_gat), fused attention-coefficient epilogue.
// 16 nodes per block; thread t owns output column t.
__global__ __launch_bounds__(256) void k_gemm_h(const float* __restrict__ x,
                                                const float* __restrict__ Wg,
                                                const float* __restrict__ att_s,
                                                const float* __restrict__ att_d,
                                                ushort_t* __restrict__ hb,
                                                float* __restrict__ a_s,
                                                float* __restrict__ a_d) {
    __shared__ float xs[16 * 128];
    int t = threadIdx.x;
    int n0 = blockIdx.x * 16;
#pragma unroll
    for (int r = 0; r < 8; ++r) {
        int idx = t + r * 256;
        xs[idx] = x[n0 * 128 + idx];
    }
    __syncthreads();
    float acc[16];
#pragma unroll
    for (int i = 0; i < 16; ++i) acc[i] = 0.f;
    for (int k = 0; k < 128; k += 4) {
        float w0 = Wg[(k + 0) * 256 + t];
        float w1 = Wg[(k + 1) * 256 + t];
        float w2 = Wg[(k + 2) * 256 + t];
        float w3 = Wg[(k + 3) * 256 + t];
#pragma unroll
        for (int i = 0; i < 16; ++i) {
            float4 xv = *(const float4*)&xs[i * 128 + k];
            acc[i] = fmaf(xv.x, w0, acc[i]);
            acc[i] = fmaf(xv.y, w1, acc[i]);
            acc[i] = fmaf(xv.z, w2, acc[i]);
            acc[i] = fmaf(xv.w, w3, acc[i]);
        }
    }
#pragma unroll
    for (int i = 0; i < 16; ++i) hb[(n0 + i) * 256 + t] = f2bf(acc[i]);

    // attention epilogue: head = t>>5, channel-in-head = t&31; att flat idx = t
    float satt = att_s[t];
    float datt = att_d[t];
#pragma unroll
    for (int i = 0; i < 16; ++i) {
        float ps = acc[i] * satt;
        float pd = acc[i] * datt;
#pragma unroll
        for (int mask = 1; mask <= 16; mask <<= 1) {
            ps += __shfl_xor(ps, mask, 64);
            pd += __shfl_xor(pd, mask, 64);
        }
        if ((t & 31) == 0) {
            a_s[(n0 + i) * 8 + (t >> 5)] = ps;
            a_d[(n0 + i) * 8 + (t >> 5)] = pd;
        }
    }
}

// ---------- CSR build ----------
__global__ __launch_bounds__(256) void k_hist(const int* __restrict__ ei,
                                              int* __restrict__ deg) {
    int e = blockIdx.x * 256 + threadIdx.x;
    if (e < N_EDGES) atomicAdd(&deg[ei[N_EDGES + e]], 1);
}

__global__ __launch_bounds__(256) void k_scan1(const int* __restrict__ deg,
                                               int* __restrict__ row,
                                               int* __restrict__ bsum) {
    __shared__ int s[256];
    int t = threadIdx.x;
    int i = blockIdx.x * 256 + t;
    int v = (i < N_NODES) ? deg[i] : 0;
    s[t] = v;
    __syncthreads();
    for (int off = 1; off < 256; off <<= 1) {
        int u = (t >= off) ? s[t - off] : 0;
        __syncthreads();
        s[t] += u;
        __syncthreads();
    }
    if (i < N_NODES) row[i] = s[t] - v;       // exclusive, block-local
    if (t == 255) bsum[blockIdx.x] = s[255];
}

// phase 2: scan the 196 block sums; also compute graph bounds (independent work)
__global__ __launch_bounds__(256) void k_scan2(int* __restrict__ bsum,
                                               const int* __restrict__ batch,
                                               int* __restrict__ gs) {
    __shared__ int s[256];
    int t = threadIdx.x;
    int v = (t < SCAN_BLOCKS) ? bsum[t] : 0;
    s[t] = v;
    __syncthreads();
    for (int off = 1; off < 256; off <<= 1) {
        int u = (t >= off) ? s[t - off] : 0;
        __syncthreads();
        s[t] += u;
        __syncthreads();
    }
    if (t < SCAN_BLOCKS) bsum[t] = s[t] - v;  // exclusive
    if (t <= NG) {
        int lo = 0, hi = N_NODES;
        while (lo < hi) {
            int mid = (lo + hi) >> 1;
            if (batch[mid] < t) lo = mid + 1; else hi = mid;
        }
        gs[t] = lo;
    }
}

// phase 3: add block offsets; zero deg for reuse as scatter cursor
__global__ __launch_bounds__(256) void k_scan3(int* __restrict__ row,
                                               const int* __restrict__ bsum,
                                               int* __restrict__ deg) {
    int i = blockIdx.x * 256 + threadIdx.x;
    if (i < N_NODES) {
        row[i] += bsum[blockIdx.x];
        deg[i] = 0;
    }
    if (i == 0) row[N_NODES] = N_EDGES;       // sum of degrees is static
}

__global__ __launch_bounds__(256) void k_scatter(const int* __restrict__ ei,
                                                 const int* __restrict__ row,
                                                 int* __restrict__ fill,
                                                 int* __restrict__ csr) {
    int e = blockIdx.x * 256 + threadIdx.x;
    if (e >= N_EDGES) return;
    int d = ei[N_EDGES + e];
    int pos = row[d] + atomicAdd(&fill[d], 1);
    csr[pos] = ei[e];
}

// ---------- fused GAT: softmax + bf16 gather-aggregate + bias + relu + @W1 ----------
// One wave per node; all LDS state wave-private -> no __syncthreads().
// Phase-2 gather unrolled x4 for memory-level parallelism (latency-bound loop).
__global__ __launch_bounds__(256) void k_gat(const int* __restrict__ row,
                                             const int* __restrict__ csr,
                                             const float* __restrict__ a_s,
                                             const float* __restrict__ a_d,
                                             const ushort_t* __restrict__ hb,
                                             const float* __restrict__ bg,
                                             const float* __restrict__ W1,
                                             float* __restrict__ y) {
    __shared__ int   s_src[4][MAXD];
    __shared__ float s_es[4][MAXD * 8];
    int g = threadIdx.x >> 6;
    int lane = threadIdx.x & 63;
    int n = blockIdx.x * 4 + g;            // N_NODES % 4 == 0
    int r0 = row[n], r1 = row[n + 1];
    int deg = r1 - r0;
    int E = deg + 1;                       // + implicit self loop
    bool cached = (E <= MAXD);
    if (cached) {
        for (int j = lane; j < deg; j += 64) s_src[g][j] = csr[r0 + j];
        if (lane == 0) s_src[g][deg] = n;  // self loop lives in the cache too
    }

    int hd = lane & 7, jl = lane >> 3;     // 8 edge-lanes x 8 heads
    float ad = a_d[n * 8 + hd];
    float pmax = -1e30f;
    for (int j = jl; j < E; j += 8) {
        int sj = cached ? s_src[g][j] : ((j < deg) ? csr[r0 + j] : n);
        float v = a_s[sj * 8 + hd] + ad;
        v = v > 0.f ? v : 0.2f * v;
        if (cached) s_es[g][j * 8 + hd] = v;
        pmax = fmaxf(pmax, v);
    }
#pragma unroll
    for (int mask = 8; mask <= 32; mask <<= 1)
        pmax = fmaxf(pmax, __shfl_xor(pmax, mask, 64));
    float psum = 0.f;
    for (int j = jl; j < E; j += 8) {
        float v;
        if (cached) v = s_es[g][j * 8 + hd];
        else {
            int sj = (j < deg) ? csr[r0 + j] : n;
            v = a_s[sj * 8 + hd] + ad;
            v = v > 0.f ? v : 0.2f * v;
        }
        psum += __expf(v - pmax);
    }
#pragma unroll
    for (int mask = 8; mask <= 32; mask <<= 1)
        psum += __shfl_xor(psum, mask, 64);
    float invden = 1.0f / psum;
    if (cached) {
        for (int j = jl; j < E; j += 8)
            s_es[g][j * 8 + hd] = __expf(s_es[g][j * 8 + hd] - pmax) * invden;
    }

    // phase 2: lane owns channels [lane*4, lane*4+4), head hd2 = lane>>3
    int hd2 = lane >> 3;
    float4 acc = make_float4(0.f, 0.f, 0.f, 0.f);
    if (cached) {
        int j = 0;
        for (; j + 4 <= E; j += 4) {
            int s0 = s_src[g][j + 0], s1 = s_src[g][j + 1];
            int s2 = s_src[g][j + 2], s3 = s_src[g][j + 3];
            float al0 = s_es[g][(j + 0) * 8 + hd2];
            float al1 = s_es[g][(j + 1) * 8 + hd2];
            float al2 = s_es[g][(j + 2) * 8 + hd2];
            float al3 = s_es[g][(j + 3) * 8 + hd2];
            uint2 u0 = *(const uint2*)(hb + s0 * HC + lane * 4);
            uint2 u1 = *(const uint2*)(hb + s1 * HC + lane * 4);
            uint2 u2 = *(const uint2*)(hb + s2 * HC + lane * 4);
            uint2 u3 = *(const uint2*)(hb + s3 * HC + lane * 4);
            acc.x = fmaf(al0, bf_lo(u0.x), acc.x);
            acc.y = fmaf(al0, bf_hi(u0.x), acc.y);
            acc.z = fmaf(al0, bf_lo(u0.y), acc.z);
            acc.w = fmaf(al0, bf_hi(u0.y), acc.w);
            acc.x = fmaf(al1, bf_lo(u1.x), acc.x);
            acc.y = fmaf(al1, bf_hi(u1.x), acc.y);
            acc.z = fmaf(al1, bf_lo(u1.y), acc.z);
            acc.w = fmaf(al1, bf_hi(u1.y), acc.w);
            acc.x = fmaf(al2, bf_lo(u2.x), acc.x);
            acc.y = fmaf(al2, bf_hi(u2.x), acc.y);
            acc.z = fmaf(al2, bf_lo(u2.y), acc.z);
            acc.w = fmaf(al2, bf_hi(u2.y), acc.w);
            acc.x = fmaf(al3, bf_lo(u3.x), acc.x);
            acc.y = fmaf(al3, bf_hi(u3.x), acc.y);
            acc.z = fmaf(al3, bf_lo(u3.y), acc.z);
            acc.w = fmaf(al3, bf_hi(u3.y), acc.w);
        }
        for (; j < E; ++j) {
            int sj = s_src[g][j];
            float alpha = s_es[g][j * 8 + hd2];
            uint2 u = *(const uint2*)(hb + sj * HC + lane * 4);
            acc.x = fmaf(alpha, bf_lo(u.x), acc.x);
            acc.y = fmaf(alpha, bf_hi(u.x), acc.y);
            acc.z = fmaf(alpha, bf_lo(u.y), acc.z);
            acc.w = fmaf(alpha, bf_hi(u.y), acc.w);
        }
    } else {
        float m2 = __shfl(pmax, hd2, 64);
        float inv2 = __shfl(invden, hd2, 64);
        float ad2 = a_d[n * 8 + hd2];
        for (int j = 0; j < E; ++j) {
            int sj = (j < deg) ? csr[r0 + j] : n;
            float v = a_s[sj * 8 + hd2] + ad2;
            v = v > 0.f ? v : 0.2f * v;
            float alpha = __expf(v - m2) * inv2;
            uint2 u = *(const uint2*)(hb + sj * HC + lane * 4);
            acc.x = fmaf(alpha, bf_lo(u.x), acc.x);
            acc.y = fmaf(alpha, bf_hi(u.x), acc.y);
            acc.z = fmaf(alpha, bf_lo(u.y), acc.z);
            acc.w = fmaf(alpha, bf_hi(u.y), acc.w);
        }
    }
    float4 b = *(const float4*)(bg + lane * 4);
    acc.x = fmaxf(acc.x + b.x, 0.f);
    acc.y = fmaxf(acc.y + b.y, 0.f);
    acc.z = fmaxf(acc.z + b.z, 0.f);
    acc.w = fmaxf(acc.w + b.w, 0.f);

    // epilogue: y[n] = out_row @ W1 (256 -> 32). Reuse s_es[g] (wave-private).
    float* srow = &s_es[g][0];
    *(float4*)(srow + lane * 4) = acc;
    int col = lane & 31;
    int c0 = (lane >> 5) * 128;            // two lanes per col, half-row each
    float yv = 0.f;
    for (int c = c0; c < c0 + 128; c += 4) {
        float4 r = *(const float4*)(srow + c);
        yv = fmaf(r.x, W1[(c + 0) * 32 + col], yv);
        yv = fmaf(r.y, W1[(c + 1) * 32 + col], yv);
        yv = fmaf(r.z, W1[(c + 2) * 32 + col], yv);
        yv = fmaf(r.w, W1[(c + 3) * 32 + col], yv);
    }
    yv += __shfl_xor(yv, 32, 64);
    if (lane < 32) y[n * 32 + col] = yv;
}

// ---------- GIN gather on y (128 B rows) + MLP layer 2, dense z write ----------
// z[n] = relu( relu(y[n] + sum_j y[src_j] + b1) @ W2 + b2 ).  8 nodes/block.
__global__ __launch_bounds__(256) void k_gin_mlp(const int* __restrict__ row,
                                                 const int* __restrict__ csr,
                                                 const float* __restrict__ y,
                                                 const float* __restrict__ b1,
                                                 const float* __restrict__ W2,
                                                 const float* __restrict__ b2,
                                                 float* __restrict__ z) {
    __shared__ float W2s[32 * 32];
    __shared__ float z1s[8][32];
    int t = threadIdx.x;
    ((float4*)W2s)[t] = ((const float4*)W2)[t];
    int node = t >> 5, col = t & 31;
    int n = blockIdx.x * 8 + node;
    int r0 = row[n], r1 = row[n + 1];
    float acc = y[n * 32 + col] + b1[col];
    int j = r0;
    for (; j + 4 <= r1; j += 4) {
        int s0 = csr[j], s1 = csr[j + 1], s2 = csr[j + 2], s3 = csr[j + 3];
        float v0 = y[s0 * 32 + col], v1 = y[s1 * 32 + col];
        float v2 = y[s2 * 32 + col], v3 = y[s3 * 32 + col];
        acc += (v0 + v1) + (v2 + v3);
    }
    for (; j < r1; ++j) acc += y[csr[j] * 32 + col];
    z1s[node][col] = fmaxf(acc, 0.f);
    __syncthreads();   // needed: W2s staging crosses waves
    float acc2 = b2[col];
    const float* zr = z1s[node];
#pragma unroll
    for (int k = 0; k < 32; k += 4) {
        float4 zv = *(const float4*)(zr + k);
        acc2 = fmaf(zv.x, W2s[(k + 0) * 32 + col], acc2);
        acc2 = fmaf(zv.y, W2s[(k + 1) * 32 + col], acc2);
        acc2 = fmaf(zv.z, W2s[(k + 2) * 32 + col], acc2);
        acc2 = fmaf(zv.w, W2s[(k + 3) * 32 + col], acc2);
    }
    z[n * 32 + col] = fmaxf(acc2, 0.f);
}

// one block per graph: mean-pool its contiguous z rows, then @Wf + bf
__global__ __launch_bounds__(128) void k_pool_final(const float* __restrict__ z,
                                                    const int* __restrict__ gs,
                                                    const float* __restrict__ Wf,
                                                    const float* __restrict__ bf,
                                                    float* __restrict__ outp) {
    __shared__ float part[4][32];
    __shared__ float sums[32];
    int g = blockIdx.x;
    int t = threadIdx.x;
    int col = t & 31, q = t >> 5;
    int r0 = gs[g], r1 = gs[g + 1];
    float s = 0.f;
    for (int r = r0 + q; r < r1; r += 4) s += z[r * 32 + col];
    part[q][col] = s;
    __syncthreads();
    if (t < 32) sums[t] = part[0][t] + part[1][t] + part[2][t] + part[3][t];
    __syncthreads();
    float inv = 1.0f / fmaxf((float)(r1 - r0), 1.0f);
    float acc = 0.f;
#pragma unroll
    for (int k = 0; k < 32; ++k)
        acc = fmaf(sums[k], Wf[k * 128 + t], acc);
    outp[g * 128 + t] = acc * inv + bf[t];
}

extern "C" void kernel_launch(void* const* d_in, const int* in_sizes, int n_in,
                              void* d_out, int out_size, void* d_ws, size_t ws_size,
                              hipStream_t stream) {
    const float* x     = (const float*)d_in[0];
    const int*   ei    = (const int*)d_in[1];
    const int*   batch = (const int*)d_in[2];
    const float* Wg    = (const float*)d_in[3];
    const float* att_s = (const float*)d_in[4];
    const float* att_d = (const float*)d_in[5];
    const float* bg    = (const float*)d_in[6];
    const float* W1    = (const float*)d_in[7];
    const float* b1    = (const float*)d_in[8];
    const float* W2    = (const float*)d_in[9];
    const float* b2    = (const float*)d_in[10];
    const float* Wf    = (const float*)d_in[11];
    const float* bf    = (const float*)d_in[12];
    float* ws = (float*)d_ws;

    ushort_t* hb  = (ushort_t*)(ws + HB_OFF);
    float* y      = ws + Y_OFF;
    float* z      = ws + Z_OFF;
    float* a_s    = ws + AS_OFF;
    float* a_d    = ws + AD_OFF;
    int*   row    = (int*)(ws + ROW_OFF);
    int*   deg    = (int*)(ws + DEG_OFF);
    int*   csr    = (int*)(ws + CSR_OFF);
    int*   gs     = (int*)(ws + GS_OFF);
    int*   bsum   = (int*)(ws + BSUM_OFF);

    // zero: deg (50000 ints)
    k_zero<<<(N_NODES / 4 + 255) / 256, 256, 0, stream>>>((float*)deg, N_NODES / 4);

    // CSR build (hierarchical scan; bounds merged into scan2)
    k_hist<<<(N_EDGES + 255) / 256, 256, 0, stream>>>(ei, deg);
    k_scan1<<<SCAN_BLOCKS, 256, 0, stream>>>(deg, row, bsum);
    k_scan2<<<1, 256, 0, stream>>>(bsum, batch, gs);
    k_scan3<<<SCAN_BLOCKS, 256, 0, stream>>>(row, bsum, deg);
    k_scatter<<<(N_EDGES + 255) / 256, 256, 0, stream>>>(ei, row, deg, csr);

    // GAT projection + attention coefficients (fused)
    k_gemm_h<<<N_NODES / 16, 256, 0, stream>>>(x, Wg, att_s, att_d, hb, a_s, a_d);
    // fused GAT: softmax + gather + bias/relu + @W1 -> y  (out never materialized)
    k_gat<<<N_NODES / 4, 256, 0, stream>>>(row, csr, a_s, a_d, hb, bg, W1, y);

    // GIN on projected y + MLP layer 2 -> z
    k_gin_mlp<<<N_NODES / 8, 256, 0, stream>>>(row, csr, y, b1, W2, b2, z);

    // per-graph mean pool + final linear
    k_pool_final<<<NG, 128, 0, stream>>>(z, gs, Wf, bf, (float*)d_out);
}